// Round 11
// baseline (270.711 us; speedup 1.0000x reference)
//
#include <hip/hip_runtime.h>
#include <math.h>
#include <stdint.h>

// Problem dims (fixed)
#define BATCH 4
#define CQ 256      // x channels
#define P 4096      // query positions (64*64)
#define CC 512      // context channels
#define PC 1024     // kv positions (32*32)
#define HID 512     // HEADS*DIM_HEAD
#define HEADS 8
#define DH 64

// Fold attention scale 1/sqrt(64) * log2(e) into Q so softmax uses exp2.
#define QSCALE 0.180336880111113703f

typedef __attribute__((ext_vector_type(8))) __fp16 f16x8;
typedef __attribute__((ext_vector_type(2))) __fp16 f16x2;
typedef __attribute__((ext_vector_type(4))) float f32x4;
typedef __attribute__((ext_vector_type(4))) unsigned int u32x4;

union H2U { f16x2 h; uint32_t u; };
union F8U { uint32_t u[4]; f16x8 v; };

__device__ __forceinline__ uint32_t pkh(float a, float b) {
    H2U z; z.h = __builtin_amdgcn_cvt_pkrtz(a, b); return z.u;
}
__device__ __forceinline__ f16x2 upk(uint32_t w) { H2U z; z.u = w; return z.h; }
__device__ __forceinline__ void split2(float a, float b, uint32_t& hw, uint32_t& lw) {
    hw = pkh(a, b);
    f16x2 h = upk(hw);
    lw = pkh(a - (float)h[0], b - (float)h[1]);
}

#if __has_builtin(__builtin_amdgcn_exp2f)
#define EXP2(x) __builtin_amdgcn_exp2f(x)
#else
#define EXP2(x) exp2f(x)
#endif

#define MFMA16(a, b, c) __builtin_amdgcn_mfma_f32_16x16x32_f16(a, b, c, 0, 0, 0)

// async global -> LDS, 16B per lane. lds base must be wave-uniform.
__device__ __forceinline__ void gl_lds16(const unsigned short* g, unsigned short* l) {
    __builtin_amdgcn_global_load_lds(
        (const __attribute__((address_space(1))) unsigned int*)g,
        (__attribute__((address_space(3))) unsigned int*)l, 16, 0, 0);
}

// ---------------------------------------------------------------------------
// Split all weights once (float4-vectorized). wq (xQSCALE) hi/lo, wk hi/lo,
// wv hi/lo, wo hi. Grid: 768 x 256, 4 elems/thread.
// ---------------------------------------------------------------------------
__global__ __launch_bounds__(256) void split_all(
    const float* __restrict__ Wq, const float* __restrict__ Wk,
    const float* __restrict__ Wv, const float* __restrict__ Wo,
    unsigned short* __restrict__ wqh, unsigned short* __restrict__ wql,
    unsigned short* __restrict__ wkh, unsigned short* __restrict__ wkl,
    unsigned short* __restrict__ wvh, unsigned short* __restrict__ wvl,
    unsigned short* __restrict__ woh)
{
    const int bid = blockIdx.x;
    const int t = threadIdx.x;
    const float* src; unsigned short *dh, *dl; int i4; float sc = 1.f;
    if (bid < 128)      { src = Wq; dh = wqh; dl = wql; i4 = bid * 256 + t; sc = QSCALE; }
    else if (bid < 384) { src = Wk; dh = wkh; dl = wkl; i4 = (bid - 128) * 256 + t; }
    else if (bid < 640) { src = Wv; dh = wvh; dl = wvl; i4 = (bid - 384) * 256 + t; }
    else                { src = Wo; dh = woh; dl = nullptr; i4 = (bid - 640) * 256 + t; }
    float4 v = *reinterpret_cast<const float4*>(src + (size_t)i4 * 4);
    uint32_t hw0, hw1, lw0, lw1;
    split2(sc * v.x, sc * v.y, hw0, lw0);
    split2(sc * v.z, sc * v.w, hw1, lw1);
    uint2 hh; hh.x = hw0; hh.y = hw1;
    *reinterpret_cast<uint2*>(dh + (size_t)i4 * 4) = hh;
    if (dl) {
        uint2 ll; ll.x = lw0; ll.y = lw1;
        *reinterpret_cast<uint2*>(dl + (size_t)i4 * 4) = ll;
    }
}

// ---------------------------------------------------------------------------
// Transpose-split both inputs in one dispatch:
//   idx < 256: x [b][256][4096] -> xh/xl [b][pos][256]
//   else:      ctx [b][512][1024] -> ctxh/ctxl [b][pos][512]
// ---------------------------------------------------------------------------
__global__ __launch_bounds__(256) void split_tr(
    const float* __restrict__ x, const float* __restrict__ ctx,
    unsigned short* __restrict__ xh, unsigned short* __restrict__ xl,
    unsigned short* __restrict__ ch, unsigned short* __restrict__ cl)
{
    const int b = blockIdx.z;
    const int idx = blockIdx.x;
    const float* in; unsigned short *Dh, *Dl; int C, Npos, p0, c0;
    if (idx < 256) {
        in = x; Dh = xh; Dl = xl; C = CQ; Npos = P;
        p0 = (idx & 63) * 64; c0 = (idx >> 6) * 64;
    } else {
        in = ctx; Dh = ch; Dl = cl; C = CC; Npos = PC;
        const int u = idx - 256;
        p0 = (u & 15) * 64; c0 = (u >> 4) * 64;
    }
    const int tid = threadIdx.x;
    const int tx = tid & 15, ty = tid >> 4;
    const float* src = in + (size_t)b * C * Npos;

    __shared__ float Ls[64][65];

    #pragma unroll
    for (int it = 0; it < 4; ++it) {
        const int clr = 16 * it + ty;
        float4 v = *reinterpret_cast<const float4*>(
            &src[(size_t)(c0 + clr) * Npos + p0 + 4 * tx]);
        Ls[clr][4 * tx + 0] = v.x; Ls[clr][4 * tx + 1] = v.y;
        Ls[clr][4 * tx + 2] = v.z; Ls[clr][4 * tx + 3] = v.w;
    }
    __syncthreads();
    #pragma unroll
    for (int it = 0; it < 4; ++it) {
        const int pl = 16 * it + ty;
        const int cc = 4 * tx;
        float v0 = Ls[cc + 0][pl], v1 = Ls[cc + 1][pl];
        float v2 = Ls[cc + 2][pl], v3 = Ls[cc + 3][pl];
        uint32_t hw0, hw1, lw0, lw1;
        split2(v0, v1, hw0, lw0);
        split2(v2, v3, hw1, lw1);
        size_t off = ((size_t)b * Npos + p0 + pl) * C + c0 + cc;
        uint2 hh; hh.x = hw0; hh.y = hw1;
        uint2 ll; ll.x = lw0; ll.y = lw1;
        *reinterpret_cast<uint2*>(Dh + off) = hh;
        *reinterpret_cast<uint2*>(Dl + off) = ll;
    }
}

// ---------------------------------------------------------------------------
// Fused Q + K + V projections, 3-term split-fp16 MFMA, one dispatch.
// blockIdx.x < 64: Q (n0 = x*64, over x-split, K=256)
// blockIdx.x in [64,96): u=x-64; u>>4==0 -> K-proj, ==1 -> V-proj (K=512)
// blockIdx.y = tileM/128. Wave = 64M x 32N.
// ---------------------------------------------------------------------------
__global__ __launch_bounds__(256) void proj_qkv(
    const unsigned short* __restrict__ wqh_, const unsigned short* __restrict__ wql_,
    const unsigned short* __restrict__ wkh_, const unsigned short* __restrict__ wkl_,
    const unsigned short* __restrict__ wvh_, const unsigned short* __restrict__ wvl_,
    const unsigned short* __restrict__ xh_, const unsigned short* __restrict__ xl_,
    const unsigned short* __restrict__ ch_, const unsigned short* __restrict__ cl_,
    unsigned short* __restrict__ qh_, unsigned short* __restrict__ ql_,
    unsigned short* __restrict__ kh_, unsigned short* __restrict__ kl_,
    unsigned short* __restrict__ vh_)
{
    const int b = blockIdx.z;
    const int bx = blockIdx.x;
    const int wid = threadIdx.x >> 6;
    const int l = threadIdx.x & 63;
    const int ln = l & 15, g = l >> 4;
    const int mb = blockIdx.y * 128 + 64 * (wid & 1);

    f32x4 acc[4][2];
    #pragma unroll
    for (int mt = 0; mt < 4; ++mt)
        #pragma unroll
        for (int nt = 0; nt < 2; ++nt) {
            f32x4 z = {0.f, 0.f, 0.f, 0.f};
            acc[mt][nt] = z;
        }

    int mode;        // 0=Q, 1=K, 2=V
    int nb;
    if (bx < 64) {
        mode = 0;
        nb = bx * 64 + 32 * (wid >> 1);
        #pragma unroll 2
        for (int k0 = 0; k0 < CQ; k0 += 32) {
            f16x8 ah[4], al[4], bh[2], bl[2];
            #pragma unroll
            for (int mt = 0; mt < 4; ++mt) {
                const size_t off = (size_t)(mb + 16 * mt + ln) * CQ + k0 + 8 * g;
                ah[mt] = *reinterpret_cast<const f16x8*>(wqh_ + off);
                al[mt] = *reinterpret_cast<const f16x8*>(wql_ + off);
            }
            #pragma unroll
            for (int nt = 0; nt < 2; ++nt) {
                const size_t off = ((size_t)b * P + nb + 16 * nt + ln) * CQ + k0 + 8 * g;
                bh[nt] = *reinterpret_cast<const f16x8*>(xh_ + off);
                bl[nt] = *reinterpret_cast<const f16x8*>(xl_ + off);
            }
            #pragma unroll
            for (int mt = 0; mt < 4; ++mt)
                #pragma unroll
                for (int nt = 0; nt < 2; ++nt) {
                    acc[mt][nt] = MFMA16(ah[mt], bh[nt], acc[mt][nt]);
                    acc[mt][nt] = MFMA16(ah[mt], bl[nt], acc[mt][nt]);
                    acc[mt][nt] = MFMA16(al[mt], bh[nt], acc[mt][nt]);
                }
        }
    } else {
        const int u = bx - 64;
        mode = 1 + (u >> 4);
        nb = (u & 15) * 64 + 32 * (wid >> 1);
        const unsigned short* Ah = (mode == 2) ? wvh_ : wkh_;
        const unsigned short* Al = (mode == 2) ? wvl_ : wkl_;
        #pragma unroll 2
        for (int k0 = 0; k0 < CC; k0 += 32) {
            f16x8 ah[4], al[4], bh[2], bl[2];
            #pragma unroll
            for (int mt = 0; mt < 4; ++mt) {
                const size_t off = (size_t)(mb + 16 * mt + ln) * CC + k0 + 8 * g;
                ah[mt] = *reinterpret_cast<const f16x8*>(Ah + off);
                al[mt] = *reinterpret_cast<const f16x8*>(Al + off);
            }
            #pragma unroll
            for (int nt = 0; nt < 2; ++nt) {
                const size_t off = ((size_t)b * PC + nb + 16 * nt + ln) * CC + k0 + 8 * g;
                bh[nt] = *reinterpret_cast<const f16x8*>(ch_ + off);
                bl[nt] = *reinterpret_cast<const f16x8*>(cl_ + off);
            }
            #pragma unroll
            for (int mt = 0; mt < 4; ++mt)
                #pragma unroll
                for (int nt = 0; nt < 2; ++nt) {
                    acc[mt][nt] = MFMA16(ah[mt], bh[nt], acc[mt][nt]);
                    acc[mt][nt] = MFMA16(ah[mt], bl[nt], acc[mt][nt]);
                    acc[mt][nt] = MFMA16(al[mt], bh[nt], acc[mt][nt]);
                }
        }
    }

    if (mode == 0) {
        #pragma unroll
        for (int mt = 0; mt < 4; ++mt) {
            const int m0 = mb + 16 * mt + 4 * g;
            const int h = m0 >> 6, cl2 = m0 & 63;
            #pragma unroll
            for (int nt = 0; nt < 2; ++nt) {
                const int pos = nb + 16 * nt + ln;
                uint32_t hw0, hw1, lw0, lw1;
                split2(acc[mt][nt][0], acc[mt][nt][1], hw0, lw0);
                split2(acc[mt][nt][2], acc[mt][nt][3], hw1, lw1);
                const size_t base = (((size_t)b * HEADS + h) * P + pos) * 64 + cl2;
                uint2 hh; hh.x = hw0; hh.y = hw1;
                uint2 ll; ll.x = lw0; ll.y = lw1;
                *reinterpret_cast<uint2*>(qh_ + base) = hh;
                *reinterpret_cast<uint2*>(ql_ + base) = ll;
            }
        }
    } else if (mode == 1) {
        #pragma unroll
        for (int mt = 0; mt < 4; ++mt) {
            const int m0 = mb + 16 * mt + 4 * g;
            const int h = m0 >> 6, cl2 = m0 & 63;
            #pragma unroll
            for (int nt = 0; nt < 2; ++nt) {
                const int pos = nb + 16 * nt + ln;
                uint32_t hw0, hw1, lw0, lw1;
                split2(acc[mt][nt][0], acc[mt][nt][1], hw0, lw0);
                split2(acc[mt][nt][2], acc[mt][nt][3], hw1, lw1);
                const size_t base = (((size_t)b * HEADS + h) * PC + pos) * 64 + cl2;
                uint2 hh; hh.x = hw0; hh.y = hw1;
                uint2 ll; ll.x = lw0; ll.y = lw1;
                *reinterpret_cast<uint2*>(kh_ + base) = hh;
                *reinterpret_cast<uint2*>(kl_ + base) = ll;
            }
        }
    } else {
        #pragma unroll
        for (int mt = 0; mt < 4; ++mt) {
            const int m0 = mb + 16 * mt + 4 * g;   // V channel 0..511
            #pragma unroll
            for (int nt = 0; nt < 2; ++nt) {
                const int pos = nb + 16 * nt + ln;
                #pragma unroll
                for (int r = 0; r < 4; ++r) {
                    unsigned short hv =
                        (unsigned short)(pkh(acc[mt][nt][r], 0.f) & 0xffffu);
                    vh_[((size_t)b * HID + m0 + r) * PC + pos] = hv;
                }
            }
        }
    }
}

// ---------------------------------------------------------------------------
// Flash attention (core identical to R9/R10; epilogue now writes O hi-only:
// 1 u32 per 2 channels -> oh [b][i][256] u32).
// ---------------------------------------------------------------------------
#define NIN 4
#define JBLK 32
#define NJT (PC / JBLK)

__global__ __launch_bounds__(256, 2) void attn_mfma(
    const unsigned short* __restrict__ qh, const unsigned short* __restrict__ ql,
    const unsigned short* __restrict__ kh, const unsigned short* __restrict__ kl,
    const unsigned short* __restrict__ vh,
    uint32_t* __restrict__ oh)
{
    const int wid = threadIdx.x >> 6;
    const int l = threadIdx.x & 63;
    const int ln = l & 15, g = l >> 4;
    const int rx = ln & 7;
    const int hb = blockIdx.x;                 // (h, b) composite
    const int h = hb & 7, b = hb >> 3;
    const int i0 = (blockIdx.y * 4 + wid) * 64;

    const size_t qbase = (size_t)(b * HEADS + h) * P * 64;
    const size_t kbase = (size_t)(b * HEADS + h) * PC * 64;
    const size_t vbase = (size_t)(b * HID + h * DH) * PC;

    __shared__ unsigned short smem[2][6144];

    f16x8 qf[NIN][2][2];
    #pragma unroll
    for (int in_ = 0; in_ < NIN; ++in_) {
        const size_t qrow = qbase + (size_t)(i0 + 16 * in_ + ln) * 64 + 8 * g;
        #pragma unroll
        for (int ks = 0; ks < 2; ++ks) {
            qf[in_][ks][0] = *reinterpret_cast<const f16x8*>(qh + qrow + 32 * ks);
            qf[in_][ks][1] = *reinterpret_cast<const f16x8*>(ql + qrow + 32 * ks);
        }
    }

    f32x4 acc[4][NIN];
    #pragma unroll
    for (int cm = 0; cm < 4; ++cm)
        #pragma unroll
        for (int in_ = 0; in_ < NIN; ++in_) {
            f32x4 z = {0.f, 0.f, 0.f, 0.f};
            acc[cm][in_] = z;
        }
    float mst[NIN], lst[NIN];
    #pragma unroll
    for (int in_ = 0; in_ < NIN; ++in_) { mst[in_] = -1e30f; lst[in_] = 0.f; }

    const int idx0 = ln + 16 * (2 * (g & 1));
    const int idx1 = idx0 + 16;
    const bool topTile = (g & 2) != 0;

    auto stage = [&](int buf, int jt) {
        const int j0 = jt * JBLK;
        #pragma unroll
        for (int t = 0; t < 3; ++t) {
            const int s = wid * 3 + t;
            unsigned short* lbase = &smem[buf][s * 512];
            const int i = (s & 3) * 64 + l;
            const int row = i >> 3, p = i & 7;
            const int slog = p ^ (row & 7);
            const unsigned short* src;
            if (s < 4) {
                src = kh + kbase + (size_t)(j0 + row) * 64 + 8 * slog;
            } else if (s < 8) {
                src = kl + kbase + (size_t)(j0 + row) * 64 + 8 * slog;
            } else {
                const int c = 2 * row + (slog >> 2);
                src = vh + vbase + (size_t)c * PC + j0 + 8 * (slog & 3);
            }
            gl_lds16(src, lbase);
        }
    };

    stage(0, 0);
    __syncthreads();

    for (int jt = 0; jt < NJT; ++jt) {
        const int cur = jt & 1;
        if (jt + 1 < NJT) stage(cur ^ 1, jt + 1);
        const unsigned short* sm = &smem[cur][0];

        f16x8 kf[2][2][2];
        #pragma unroll
        for (int jm = 0; jm < 2; ++jm)
            #pragma unroll
            for (int ks = 0; ks < 2; ++ks) {
                const int base = (16 * jm + ln) * 64 + 8 * ((4 * ks + g) ^ rx);
                kf[jm][ks][0] = *reinterpret_cast<const f16x8*>(sm + base);
                kf[jm][ks][1] = *reinterpret_cast<const f16x8*>(sm + 2048 + base);
            }
        f16x8 vf[4];
        #pragma unroll
        for (int cm = 0; cm < 4; ++cm) {
            const int vaddr = 4096 + (8 * cm + (ln >> 1)) * 64 +
                              8 * ((4 * (ln & 1) + g) ^ (ln >> 1));
            vf[cm] = *reinterpret_cast<const f16x8*>(sm + vaddr);
        }

        f32x4 s[2][NIN];
        #pragma unroll
        for (int jm = 0; jm < 2; ++jm)
            #pragma unroll
            for (int in_ = 0; in_ < NIN; ++in_) {
                f32x4 z = {0.f, 0.f, 0.f, 0.f};
                s[jm][in_] = z;
            }
        __builtin_amdgcn_s_setprio(1);
        #pragma unroll
        for (int jm = 0; jm < 2; ++jm)
            #pragma unroll
            for (int ks = 0; ks < 2; ++ks)
                #pragma unroll
                for (int in_ = 0; in_ < NIN; ++in_) {
                    s[jm][in_] = MFMA16(kf[jm][ks][0], qf[in_][ks][0], s[jm][in_]);
                    s[jm][in_] = MFMA16(kf[jm][ks][0], qf[in_][ks][1], s[jm][in_]);
                    s[jm][in_] = MFMA16(kf[jm][ks][1], qf[in_][ks][0], s[jm][in_]);
                }
        __builtin_amdgcn_s_setprio(0);

        #pragma unroll
        for (int in_ = 0; in_ < NIN; ++in_) {
            float tmx = fmaxf(fmaxf(fmaxf(s[0][in_][0], s[0][in_][1]),
                                    fmaxf(s[0][in_][2], s[0][in_][3])),
                              fmaxf(fmaxf(s[1][in_][0], s[1][in_][1]),
                                    fmaxf(s[1][in_][2], s[1][in_][3])));
            tmx = fmaxf(tmx, __shfl_xor(tmx, 16, 64));
            tmx = fmaxf(tmx, __shfl_xor(tmx, 32, 64));
            const bool skip = __all(tmx <= mst[in_] + 1.0f);
            float mnew = skip ? mst[in_] : fmaxf(mst[in_], tmx);
            float rs = 0.f;
            #pragma unroll
            for (int jm = 0; jm < 2; ++jm)
                #pragma unroll
                for (int r = 0; r < 4; ++r) {
                    float p = EXP2(s[jm][in_][r] - mnew);
                    s[jm][in_][r] = p; rs += p;
                }
            rs += __shfl_xor(rs, 16, 64);
            rs += __shfl_xor(rs, 32, 64);
            if (skip) {
                lst[in_] += rs;
            } else {
                float fac = EXP2(mst[in_] - mnew);
                lst[in_] = lst[in_] * fac + rs;
                mst[in_] = mnew;
                #pragma unroll
                for (int cm = 0; cm < 4; ++cm) acc[cm][in_] *= fac;
            }

            int w00 = (int)pkh(s[0][in_][0], s[0][in_][1]);
            int w01 = (int)pkh(s[0][in_][2], s[0][in_][3]);
            int w10 = (int)pkh(s[1][in_][0], s[1][in_][1]);
            int w11 = (int)pkh(s[1][in_][2], s[1][in_][3]);

            int a0 = __shfl(w00, idx0, 64), a1 = __shfl(w01, idx0, 64);
            int a2 = __shfl(w00, idx1, 64), a3 = __shfl(w01, idx1, 64);
            int b0 = __shfl(w10, idx0, 64), b1 = __shfl(w11, idx0, 64);
            int b2 = __shfl(w10, idx1, 64), b3 = __shfl(w11, idx1, 64);
            F8U fu;
            fu.u[0] = (uint32_t)(topTile ? b0 : a0);
            fu.u[1] = (uint32_t)(topTile ? b1 : a1);
            fu.u[2] = (uint32_t)(topTile ? b2 : a2);
            fu.u[3] = (uint32_t)(topTile ? b3 : a3);

            __builtin_amdgcn_s_setprio(1);
            #pragma unroll
            for (int cm = 0; cm < 4; ++cm)
                acc[cm][in_] = MFMA16(vf[cm], fu.v, acc[cm][in_]);
            __builtin_amdgcn_s_setprio(0);
        }

        __syncthreads();
    }

    // epilogue: O/l -> fp16 hi only, 1 u32 per 2 channels
    #pragma unroll
    for (int in_ = 0; in_ < NIN; ++in_) {
        float inv = 1.0f / lst[in_];
        int i = i0 + 16 * in_ + ln;
        #pragma unroll
        for (int cm = 0; cm < 4; ++cm) {
            f32x4 o4 = acc[cm][in_] * inv;
            uint2 wv;
            wv.x = pkh(o4[0], o4[1]);
            wv.y = pkh(o4[2], o4[3]);
            size_t idx = ((size_t)b * P + i) * 256 + (size_t)(32 * h + 8 * cm + 2 * g);
            *reinterpret_cast<uint2*>(oh + idx) = wv;
        }
    }
}

// ---------------------------------------------------------------------------
// Output projection: out = Wo_h @ O_h + bo (1-term fp16 MFMA).
// ---------------------------------------------------------------------------
__global__ __launch_bounds__(256, 4) void out_proj(
    const unsigned short* __restrict__ woh, const uint32_t* __restrict__ oh,
    const float* __restrict__ bo, float* __restrict__ out)
{
    const int wid = threadIdx.x >> 6;
    const int l = threadIdx.x & 63;
    const int ln = l & 15, g = l >> 4;
    const int ibase = blockIdx.x * 128 + wid * 32;
    const int otile = blockIdx.y * 32;
    const int b = blockIdx.z;

    f32x4 acc[2][2];
    #pragma unroll
    for (int mt = 0; mt < 2; ++mt)
        #pragma unroll
        for (int nt = 0; nt < 2; ++nt) {
            f32x4 z = {0.f, 0.f, 0.f, 0.f};
            acc[mt][nt] = z;
        }

    #pragma unroll
    for (int ks = 0; ks < 16; ++ks) {
        const int c0 = 32 * ks + 8 * g;
        f16x8 wf[2];
        #pragma unroll
        for (int mt = 0; mt < 2; ++mt)
            wf[mt] = *reinterpret_cast<const f16x8*>(
                woh + (size_t)(otile + 16 * mt + ln) * HID + c0);
        #pragma unroll
        for (int nt = 0; nt < 2; ++nt) {
            const size_t obase = ((size_t)b * P + ibase + 16 * nt + ln) * 256 + (c0 >> 1);
            u32x4 A = *reinterpret_cast<const u32x4*>(oh + obase);
            F8U bh;
            bh.u[0] = A[0]; bh.u[1] = A[1]; bh.u[2] = A[2]; bh.u[3] = A[3];
            #pragma unroll
            for (int mt = 0; mt < 2; ++mt)
                acc[mt][nt] = MFMA16(wf[mt], bh.v, acc[mt][nt]);
        }
    }

    #pragma unroll
    for (int mt = 0; mt < 2; ++mt)
        #pragma unroll
        for (int r = 0; r < 4; ++r) {
            int o_ = otile + 16 * mt + 4 * g + r;
            float bv = bo[o_];
            #pragma unroll
            for (int nt = 0; nt < 2; ++nt)
                out[((size_t)b * CQ + o_) * P + ibase + 16 * nt + ln] =
                    acc[mt][nt][r] + bv;
        }
}

extern "C" void kernel_launch(void* const* d_in, const int* in_sizes, int n_in,
                              void* d_out, int out_size, void* d_ws, size_t ws_size,
                              hipStream_t stream) {
    (void)in_sizes; (void)n_in; (void)out_size; (void)ws_size;
    const float* x   = (const float*)d_in[0];
    const float* ctx = (const float*)d_in[1];
    const float* Wq  = (const float*)d_in[2];
    const float* Wk  = (const float*)d_in[3];
    const float* Wv  = (const float*)d_in[4];
    const float* Wo  = (const float*)d_in[5];
    const float* bo  = (const float*)d_in[6];
    float* out = (float*)d_out;

    // Workspace (ushort units). oh (u32[4194304] = 16.8 MB) aliases xh/xl,
    // which are dead before attn writes oh.
    unsigned short* ws = (unsigned short*)d_ws;
    uint32_t* oh         = (uint32_t*)ws;            // 4194304 u32
    unsigned short* xh   = ws;                       // 4194304
    unsigned short* xl   = ws + (size_t)4194304;
    unsigned short* ctxh = ws + (size_t)8388608;     // 2097152
    unsigned short* ctxl = ws + (size_t)10485760;
    unsigned short* qh   = ws + (size_t)16777216;    // 8388608
    unsigned short* ql   = qh + (size_t)8388608;
    unsigned short* kh   = ql + (size_t)8388608;     // 2097152
    unsigned short* kl   = kh + (size_t)2097152;
    unsigned short* vh   = kl + (size_t)2097152;     // 2097152
    unsigned short* woh  = vh + (size_t)2097152;     // 131072
    unsigned short* wqh  = woh + (size_t)131072;     // 131072
    unsigned short* wql  = wqh + (size_t)131072;
    unsigned short* wkh  = wql + (size_t)131072;     // 262144
    unsigned short* wkl  = wkh + (size_t)262144;
    unsigned short* wvh  = wkl + (size_t)262144;
    unsigned short* wvl  = wvh + (size_t)262144;

    dim3 blk(256);
    // 1. weight splits (float4-vectorized)
    split_all<<<dim3(768), blk, 0, stream>>>(
        Wq, Wk, Wv, Wo, wqh, wql, wkh, wkl, wvh, wvl, woh);
    // 2. input transpose-splits (x + ctx, one dispatch)
    split_tr<<<dim3(384, 1, BATCH), blk, 0, stream>>>(
        x, ctx, xh, xl, ctxh, ctxl);
    // 3. fused Q/K/V projections (MFMA)
    proj_qkv<<<dim3(96, 4, BATCH), blk, 0, stream>>>(
        wqh, wql, wkh, wkl, wvh, wvl, xh, xl, ctxh, ctxl, qh, ql, kh, kl, vh);
    // 4. attention -> oh (hi-only; clobbers xh/xl — dead by now)
    attn_mfma<<<dim3(HEADS * BATCH, P / 256), blk, 0, stream>>>(
        qh, ql, kh, kl, vh, oh);
    // 5. out = Wo @ O + bo
    out_proj<<<dim3(P / 128, CQ / 32, BATCH), blk, 0, stream>>>(
        woh, oh, bo, out);
}

// Round 12
// 200.009 us; speedup vs baseline: 1.3535x; 1.3535x over previous
//
#include <hip/hip_runtime.h>
#include <math.h>
#include <stdint.h>

// Problem dims (fixed)
#define BATCH 4
#define CQ 256      // x channels
#define P 4096      // query positions (64*64)
#define CC 512      // context channels
#define PC 1024     // kv positions (32*32)
#define HID 512     // HEADS*DIM_HEAD
#define HEADS 8
#define DH 64

// Fold attention scale 1/sqrt(64) * log2(e) into Q so softmax uses exp2.
#define QSCALE 0.180336880111113703f

typedef __attribute__((ext_vector_type(8))) __fp16 f16x8;
typedef __attribute__((ext_vector_type(2))) __fp16 f16x2;
typedef __attribute__((ext_vector_type(4))) float f32x4;
typedef __attribute__((ext_vector_type(4))) unsigned int u32x4;

union H2U { f16x2 h; uint32_t u; };
union F8U { uint32_t u[4]; f16x8 v; };

__device__ __forceinline__ uint32_t pkh(float a, float b) {
    H2U z; z.h = __builtin_amdgcn_cvt_pkrtz(a, b); return z.u;
}
__device__ __forceinline__ f16x2 upk(uint32_t w) { H2U z; z.u = w; return z.h; }
__device__ __forceinline__ void split2(float a, float b, uint32_t& hw, uint32_t& lw) {
    hw = pkh(a, b);
    f16x2 h = upk(hw);
    lw = pkh(a - (float)h[0], b - (float)h[1]);
}

#if __has_builtin(__builtin_amdgcn_exp2f)
#define EXP2(x) __builtin_amdgcn_exp2f(x)
#else
#define EXP2(x) exp2f(x)
#endif

#define MFMA16(a, b, c) __builtin_amdgcn_mfma_f32_16x16x32_f16(a, b, c, 0, 0, 0)

// async global -> LDS, 16B per lane. lds base must be wave-uniform.
__device__ __forceinline__ void gl_lds16(const unsigned short* g, unsigned short* l) {
    __builtin_amdgcn_global_load_lds(
        (const __attribute__((address_space(1))) unsigned int*)g,
        (__attribute__((address_space(3))) unsigned int*)l, 16, 0, 0);
}

// ---------------------------------------------------------------------------
// Split all weights once (float4-vectorized).
// wq/wk/wv -> octet layout [k/8][m][8] hi+lo (wq pre-scaled by QSCALE);
// wo -> linear [o][c] hi only.
// ---------------------------------------------------------------------------
__global__ __launch_bounds__(256) void split_all(
    const float* __restrict__ Wq, const float* __restrict__ Wk,
    const float* __restrict__ Wv, const float* __restrict__ Wo,
    unsigned short* __restrict__ wqh, unsigned short* __restrict__ wql,
    unsigned short* __restrict__ wkh, unsigned short* __restrict__ wkl,
    unsigned short* __restrict__ wvh, unsigned short* __restrict__ wvl,
    unsigned short* __restrict__ woh)
{
    const int bid = blockIdx.x;
    const int t = threadIdx.x;
    const float* src; unsigned short *dh, *dl; int i4; float sc = 1.f; int ksh;
    if (bid < 128)      { src = Wq; dh = wqh; dl = wql; i4 = bid * 256 + t; sc = QSCALE; ksh = 8; }
    else if (bid < 384) { src = Wk; dh = wkh; dl = wkl; i4 = (bid - 128) * 256 + t; ksh = 9; }
    else if (bid < 640) { src = Wv; dh = wvh; dl = wvl; i4 = (bid - 384) * 256 + t; ksh = 9; }
    else                { src = Wo; dh = woh; dl = nullptr; i4 = (bid - 640) * 256 + t; ksh = 0; }
    float4 v = *reinterpret_cast<const float4*>(src + (size_t)i4 * 4);
    uint32_t hw0, hw1, lw0, lw1;
    split2(sc * v.x, sc * v.y, hw0, lw0);
    split2(sc * v.z, sc * v.w, hw1, lw1);
    uint2 hh; hh.x = hw0; hh.y = hw1;
    if (ksh) {
        const int lin = i4 * 4;
        const int m = lin >> ksh;
        const int k = lin & ((1 << ksh) - 1);
        const size_t off = ((size_t)(k >> 3) * HID + m) * 8 + (k & 7);
        *reinterpret_cast<uint2*>(dh + off) = hh;
        uint2 ll; ll.x = lw0; ll.y = lw1;
        *reinterpret_cast<uint2*>(dl + off) = ll;
    } else {
        *reinterpret_cast<uint2*>(dh + (size_t)i4 * 4) = hh;
    }
}

// ---------------------------------------------------------------------------
// Transpose-split both inputs to octet layout [b][k/8][pos][8] fp16 hi/lo.
//   idx < 256: x [b][256][4096];  else: ctx [b][512][1024]
// ---------------------------------------------------------------------------
__global__ __launch_bounds__(256) void split_tr(
    const float* __restrict__ x, const float* __restrict__ ctx,
    unsigned short* __restrict__ xh, unsigned short* __restrict__ xl,
    unsigned short* __restrict__ ch, unsigned short* __restrict__ cl)
{
    const int b = blockIdx.z;
    const int idx = blockIdx.x;
    const float* in; unsigned short *Dh, *Dl; int C, Npos, p0, c0;
    if (idx < 256) {
        in = x; Dh = xh; Dl = xl; C = CQ; Npos = P;
        p0 = (idx & 63) * 64; c0 = (idx >> 6) * 64;
    } else {
        in = ctx; Dh = ch; Dl = cl; C = CC; Npos = PC;
        const int u = idx - 256;
        p0 = (u & 15) * 64; c0 = (u >> 4) * 64;
    }
    const int tid = threadIdx.x;
    const int tx = tid & 15, ty = tid >> 4;
    const float* src = in + (size_t)b * C * Npos;

    __shared__ float Ls[64][65];

    #pragma unroll
    for (int it = 0; it < 4; ++it) {
        const int clr = 16 * it + ty;
        float4 v = *reinterpret_cast<const float4*>(
            &src[(size_t)(c0 + clr) * Npos + p0 + 4 * tx]);
        Ls[clr][4 * tx + 0] = v.x; Ls[clr][4 * tx + 1] = v.y;
        Ls[clr][4 * tx + 2] = v.z; Ls[clr][4 * tx + 3] = v.w;
    }
    __syncthreads();

    // 512 (oct,pos) entries of 16B; wave-uniform octet, lane = pos.
    const int l = tid & 63, wv_ = tid >> 6;
    #pragma unroll
    for (int pass = 0; pass < 2; ++pass) {
        const int oct = pass * 4 + wv_;
        float v0 = Ls[oct * 8 + 0][l], v1 = Ls[oct * 8 + 1][l];
        float v2 = Ls[oct * 8 + 2][l], v3 = Ls[oct * 8 + 3][l];
        float v4 = Ls[oct * 8 + 4][l], v5 = Ls[oct * 8 + 5][l];
        float v6 = Ls[oct * 8 + 6][l], v7 = Ls[oct * 8 + 7][l];
        uint32_t h0, h1, h2, h3, l0, l1, l2, l3;
        split2(v0, v1, h0, l0); split2(v2, v3, h1, l1);
        split2(v4, v5, h2, l2); split2(v6, v7, h3, l3);
        const size_t base =
            ((size_t)(b * (C >> 3) + (c0 >> 3) + oct) * Npos + p0 + l) * 8;
        u32x4 hh; hh[0] = h0; hh[1] = h1; hh[2] = h2; hh[3] = h3;
        u32x4 ll; ll[0] = l0; ll[1] = l1; ll[2] = l2; ll[3] = l3;
        *reinterpret_cast<u32x4*>(Dh + base) = hh;
        *reinterpret_cast<u32x4*>(Dl + base) = ll;
    }
}

// ---------------------------------------------------------------------------
// Fused Q + K + V projections, 3-term split-fp16 MFMA, coalesced octet loads.
// blockIdx.x < 64: Q; in [64,96): K (u>>4==0) / V (==1).
// ---------------------------------------------------------------------------
__global__ __launch_bounds__(256) void proj_qkv(
    const unsigned short* __restrict__ wqh_, const unsigned short* __restrict__ wql_,
    const unsigned short* __restrict__ wkh_, const unsigned short* __restrict__ wkl_,
    const unsigned short* __restrict__ wvh_, const unsigned short* __restrict__ wvl_,
    const unsigned short* __restrict__ xh_, const unsigned short* __restrict__ xl_,
    const unsigned short* __restrict__ ch_, const unsigned short* __restrict__ cl_,
    unsigned short* __restrict__ qh_, unsigned short* __restrict__ ql_,
    unsigned short* __restrict__ kh_, unsigned short* __restrict__ kl_,
    unsigned short* __restrict__ vh_)
{
    const int b = blockIdx.z;
    const int bx = blockIdx.x;
    const int wid = threadIdx.x >> 6;
    const int l = threadIdx.x & 63;
    const int ln = l & 15, g = l >> 4;
    const int mb = blockIdx.y * 128 + 64 * (wid & 1);

    f32x4 acc[4][2];
    #pragma unroll
    for (int mt = 0; mt < 4; ++mt)
        #pragma unroll
        for (int nt = 0; nt < 2; ++nt) {
            f32x4 z = {0.f, 0.f, 0.f, 0.f};
            acc[mt][nt] = z;
        }

    int mode;        // 0=Q, 1=K, 2=V
    int nb;
    if (bx < 64) {
        mode = 0;
        nb = bx * 64 + 32 * (wid >> 1);
        #pragma unroll 4
        for (int k0 = 0; k0 < CQ; k0 += 32) {
            const int kq = (k0 >> 3) + g;
            f16x8 ah[4], al[4], bh[2], bl[2];
            #pragma unroll
            for (int mt = 0; mt < 4; ++mt) {
                const size_t off = ((size_t)kq * HID + mb + 16 * mt + ln) * 8;
                ah[mt] = *reinterpret_cast<const f16x8*>(wqh_ + off);
                al[mt] = *reinterpret_cast<const f16x8*>(wql_ + off);
            }
            #pragma unroll
            for (int nt = 0; nt < 2; ++nt) {
                const size_t off = ((size_t)(b * 32 + kq) * P + nb + 16 * nt + ln) * 8;
                bh[nt] = *reinterpret_cast<const f16x8*>(xh_ + off);
                bl[nt] = *reinterpret_cast<const f16x8*>(xl_ + off);
            }
            #pragma unroll
            for (int mt = 0; mt < 4; ++mt)
                #pragma unroll
                for (int nt = 0; nt < 2; ++nt) {
                    acc[mt][nt] = MFMA16(ah[mt], bh[nt], acc[mt][nt]);
                    acc[mt][nt] = MFMA16(ah[mt], bl[nt], acc[mt][nt]);
                    acc[mt][nt] = MFMA16(al[mt], bh[nt], acc[mt][nt]);
                }
        }
    } else {
        const int u = bx - 64;
        mode = 1 + (u >> 4);
        nb = (u & 15) * 64 + 32 * (wid >> 1);
        const unsigned short* Ah = (mode == 2) ? wvh_ : wkh_;
        const unsigned short* Al = (mode == 2) ? wvl_ : wkl_;
        #pragma unroll 4
        for (int k0 = 0; k0 < CC; k0 += 32) {
            const int kq = (k0 >> 3) + g;
            f16x8 ah[4], al[4], bh[2], bl[2];
            #pragma unroll
            for (int mt = 0; mt < 4; ++mt) {
                const size_t off = ((size_t)kq * HID + mb + 16 * mt + ln) * 8;
                ah[mt] = *reinterpret_cast<const f16x8*>(Ah + off);
                al[mt] = *reinterpret_cast<const f16x8*>(Al + off);
            }
            #pragma unroll
            for (int nt = 0; nt < 2; ++nt) {
                const size_t off = ((size_t)(b * 64 + kq) * PC + nb + 16 * nt + ln) * 8;
                bh[nt] = *reinterpret_cast<const f16x8*>(ch_ + off);
                bl[nt] = *reinterpret_cast<const f16x8*>(cl_ + off);
            }
            #pragma unroll
            for (int mt = 0; mt < 4; ++mt)
                #pragma unroll
                for (int nt = 0; nt < 2; ++nt) {
                    acc[mt][nt] = MFMA16(ah[mt], bh[nt], acc[mt][nt]);
                    acc[mt][nt] = MFMA16(ah[mt], bl[nt], acc[mt][nt]);
                    acc[mt][nt] = MFMA16(al[mt], bh[nt], acc[mt][nt]);
                }
        }
    }

    if (mode == 0) {
        #pragma unroll
        for (int mt = 0; mt < 4; ++mt) {
            const int m0 = mb + 16 * mt + 4 * g;
            const int h = m0 >> 6, cl2 = m0 & 63;
            #pragma unroll
            for (int nt = 0; nt < 2; ++nt) {
                const int pos = nb + 16 * nt + ln;
                uint32_t hw0, hw1, lw0, lw1;
                split2(acc[mt][nt][0], acc[mt][nt][1], hw0, lw0);
                split2(acc[mt][nt][2], acc[mt][nt][3], hw1, lw1);
                const size_t base = (((size_t)b * HEADS + h) * P + pos) * 64 + cl2;
                uint2 hh; hh.x = hw0; hh.y = hw1;
                uint2 ll; ll.x = lw0; ll.y = lw1;
                *reinterpret_cast<uint2*>(qh_ + base) = hh;
                *reinterpret_cast<uint2*>(ql_ + base) = ll;
            }
        }
    } else if (mode == 1) {
        #pragma unroll
        for (int mt = 0; mt < 4; ++mt) {
            const int m0 = mb + 16 * mt + 4 * g;
            const int h = m0 >> 6, cl2 = m0 & 63;
            #pragma unroll
            for (int nt = 0; nt < 2; ++nt) {
                const int pos = nb + 16 * nt + ln;
                uint32_t hw0, hw1, lw0, lw1;
                split2(acc[mt][nt][0], acc[mt][nt][1], hw0, lw0);
                split2(acc[mt][nt][2], acc[mt][nt][3], hw1, lw1);
                const size_t base = (((size_t)b * HEADS + h) * PC + pos) * 64 + cl2;
                uint2 hh; hh.x = hw0; hh.y = hw1;
                uint2 ll; ll.x = lw0; ll.y = lw1;
                *reinterpret_cast<uint2*>(kh_ + base) = hh;
                *reinterpret_cast<uint2*>(kl_ + base) = ll;
            }
        }
    } else {
        #pragma unroll
        for (int mt = 0; mt < 4; ++mt) {
            const int m0 = mb + 16 * mt + 4 * g;   // V channel 0..511
            #pragma unroll
            for (int nt = 0; nt < 2; ++nt) {
                const int pos = nb + 16 * nt + ln;
                #pragma unroll
                for (int r = 0; r < 4; ++r) {
                    unsigned short hv =
                        (unsigned short)(pkh(acc[mt][nt][r], 0.f) & 0xffffu);
                    vh_[((size_t)b * HID + m0 + r) * PC + pos] = hv;
                }
            }
        }
    }
}

// ---------------------------------------------------------------------------
// Flash attention (core identical to R9-R11; epilogue writes O hi-only to
// TRANSPOSED oh [b][chan-pair 256][pos] u32, coalesced 4B stores).
// ---------------------------------------------------------------------------
#define NIN 4
#define JBLK 32
#define NJT (PC / JBLK)

__global__ __launch_bounds__(256, 2) void attn_mfma(
    const unsigned short* __restrict__ qh, const unsigned short* __restrict__ ql,
    const unsigned short* __restrict__ kh, const unsigned short* __restrict__ kl,
    const unsigned short* __restrict__ vh,
    uint32_t* __restrict__ oh)
{
    const int wid = threadIdx.x >> 6;
    const int l = threadIdx.x & 63;
    const int ln = l & 15, g = l >> 4;
    const int rx = ln & 7;
    const int hb = blockIdx.x;                 // (h, b) composite
    const int h = hb & 7, b = hb >> 3;
    const int i0 = (blockIdx.y * 4 + wid) * 64;

    const size_t qbase = (size_t)(b * HEADS + h) * P * 64;
    const size_t kbase = (size_t)(b * HEADS + h) * PC * 64;
    const size_t vbase = (size_t)(b * HID + h * DH) * PC;

    __shared__ unsigned short smem[2][6144];

    f16x8 qf[NIN][2][2];
    #pragma unroll
    for (int in_ = 0; in_ < NIN; ++in_) {
        const size_t qrow = qbase + (size_t)(i0 + 16 * in_ + ln) * 64 + 8 * g;
        #pragma unroll
        for (int ks = 0; ks < 2; ++ks) {
            qf[in_][ks][0] = *reinterpret_cast<const f16x8*>(qh + qrow + 32 * ks);
            qf[in_][ks][1] = *reinterpret_cast<const f16x8*>(ql + qrow + 32 * ks);
        }
    }

    f32x4 acc[4][NIN];
    #pragma unroll
    for (int cm = 0; cm < 4; ++cm)
        #pragma unroll
        for (int in_ = 0; in_ < NIN; ++in_) {
            f32x4 z = {0.f, 0.f, 0.f, 0.f};
            acc[cm][in_] = z;
        }
    float mst[NIN], lst[NIN];
    #pragma unroll
    for (int in_ = 0; in_ < NIN; ++in_) { mst[in_] = -1e30f; lst[in_] = 0.f; }

    const int idx0 = ln + 16 * (2 * (g & 1));
    const int idx1 = idx0 + 16;
    const bool topTile = (g & 2) != 0;

    auto stage = [&](int buf, int jt) {
        const int j0 = jt * JBLK;
        #pragma unroll
        for (int t = 0; t < 3; ++t) {
            const int s = wid * 3 + t;
            unsigned short* lbase = &smem[buf][s * 512];
            const int i = (s & 3) * 64 + l;
            const int row = i >> 3, p = i & 7;
            const int slog = p ^ (row & 7);
            const unsigned short* src;
            if (s < 4) {
                src = kh + kbase + (size_t)(j0 + row) * 64 + 8 * slog;
            } else if (s < 8) {
                src = kl + kbase + (size_t)(j0 + row) * 64 + 8 * slog;
            } else {
                const int c = 2 * row + (slog >> 2);
                src = vh + vbase + (size_t)c * PC + j0 + 8 * (slog & 3);
            }
            gl_lds16(src, lbase);
        }
    };

    stage(0, 0);
    __syncthreads();

    for (int jt = 0; jt < NJT; ++jt) {
        const int cur = jt & 1;
        if (jt + 1 < NJT) stage(cur ^ 1, jt + 1);
        const unsigned short* sm = &smem[cur][0];

        f16x8 kf[2][2][2];
        #pragma unroll
        for (int jm = 0; jm < 2; ++jm)
            #pragma unroll
            for (int ks = 0; ks < 2; ++ks) {
                const int base = (16 * jm + ln) * 64 + 8 * ((4 * ks + g) ^ rx);
                kf[jm][ks][0] = *reinterpret_cast<const f16x8*>(sm + base);
                kf[jm][ks][1] = *reinterpret_cast<const f16x8*>(sm + 2048 + base);
            }
        f16x8 vf[4];
        #pragma unroll
        for (int cm = 0; cm < 4; ++cm) {
            const int vaddr = 4096 + (8 * cm + (ln >> 1)) * 64 +
                              8 * ((4 * (ln & 1) + g) ^ (ln >> 1));
            vf[cm] = *reinterpret_cast<const f16x8*>(sm + vaddr);
        }

        f32x4 s[2][NIN];
        #pragma unroll
        for (int jm = 0; jm < 2; ++jm)
            #pragma unroll
            for (int in_ = 0; in_ < NIN; ++in_) {
                f32x4 z = {0.f, 0.f, 0.f, 0.f};
                s[jm][in_] = z;
            }
        __builtin_amdgcn_s_setprio(1);
        #pragma unroll
        for (int jm = 0; jm < 2; ++jm)
            #pragma unroll
            for (int ks = 0; ks < 2; ++ks)
                #pragma unroll
                for (int in_ = 0; in_ < NIN; ++in_) {
                    s[jm][in_] = MFMA16(kf[jm][ks][0], qf[in_][ks][0], s[jm][in_]);
                    s[jm][in_] = MFMA16(kf[jm][ks][0], qf[in_][ks][1], s[jm][in_]);
                    s[jm][in_] = MFMA16(kf[jm][ks][1], qf[in_][ks][0], s[jm][in_]);
                }
        __builtin_amdgcn_s_setprio(0);

        #pragma unroll
        for (int in_ = 0; in_ < NIN; ++in_) {
            float tmx = fmaxf(fmaxf(fmaxf(s[0][in_][0], s[0][in_][1]),
                                    fmaxf(s[0][in_][2], s[0][in_][3])),
                              fmaxf(fmaxf(s[1][in_][0], s[1][in_][1]),
                                    fmaxf(s[1][in_][2], s[1][in_][3])));
            tmx = fmaxf(tmx, __shfl_xor(tmx, 16, 64));
            tmx = fmaxf(tmx, __shfl_xor(tmx, 32, 64));
            const bool skip = __all(tmx <= mst[in_] + 1.0f);
            float mnew = skip ? mst[in_] : fmaxf(mst[in_], tmx);
            float rs = 0.f;
            #pragma unroll
            for (int jm = 0; jm < 2; ++jm)
                #pragma unroll
                for (int r = 0; r < 4; ++r) {
                    float p = EXP2(s[jm][in_][r] - mnew);
                    s[jm][in_][r] = p; rs += p;
                }
            rs += __shfl_xor(rs, 16, 64);
            rs += __shfl_xor(rs, 32, 64);
            if (skip) {
                lst[in_] += rs;
            } else {
                float fac = EXP2(mst[in_] - mnew);
                lst[in_] = lst[in_] * fac + rs;
                mst[in_] = mnew;
                #pragma unroll
                for (int cm = 0; cm < 4; ++cm) acc[cm][in_] *= fac;
            }

            int w00 = (int)pkh(s[0][in_][0], s[0][in_][1]);
            int w01 = (int)pkh(s[0][in_][2], s[0][in_][3]);
            int w10 = (int)pkh(s[1][in_][0], s[1][in_][1]);
            int w11 = (int)pkh(s[1][in_][2], s[1][in_][3]);

            int a0 = __shfl(w00, idx0, 64), a1 = __shfl(w01, idx0, 64);
            int a2 = __shfl(w00, idx1, 64), a3 = __shfl(w01, idx1, 64);
            int b0 = __shfl(w10, idx0, 64), b1 = __shfl(w11, idx0, 64);
            int b2 = __shfl(w10, idx1, 64), b3 = __shfl(w11, idx1, 64);
            F8U fu;
            fu.u[0] = (uint32_t)(topTile ? b0 : a0);
            fu.u[1] = (uint32_t)(topTile ? b1 : a1);
            fu.u[2] = (uint32_t)(topTile ? b2 : a2);
            fu.u[3] = (uint32_t)(topTile ? b3 : a3);

            __builtin_amdgcn_s_setprio(1);
            #pragma unroll
            for (int cm = 0; cm < 4; ++cm)
                acc[cm][in_] = MFMA16(vf[cm], fu.v, acc[cm][in_]);
            __builtin_amdgcn_s_setprio(0);
        }

        __syncthreads();
    }

    // epilogue: O/l -> fp16 hi only, transposed [b][cp][pos], coalesced 4B
    #pragma unroll
    for (int in_ = 0; in_ < NIN; ++in_) {
        float inv = 1.0f / lst[in_];
        int i = i0 + 16 * in_ + ln;
        #pragma unroll
        for (int cm = 0; cm < 4; ++cm) {
            f32x4 o4 = acc[cm][in_] * inv;
            const int cp = 32 * h + 8 * cm + 2 * g;
            const size_t idx = ((size_t)b * 256 + cp) * P + i;
            oh[idx] = pkh(o4[0], o4[1]);
            oh[idx + P] = pkh(o4[2], o4[3]);
        }
    }
}

// ---------------------------------------------------------------------------
// Output projection: out = Wo_h @ O_h + bo (1-term fp16 MFMA), coalesced
// B-loads from transposed oh [b][cp][pos].
// ---------------------------------------------------------------------------
__global__ __launch_bounds__(256, 4) void out_proj(
    const unsigned short* __restrict__ woh, const uint32_t* __restrict__ oh,
    const float* __restrict__ bo, float* __restrict__ out)
{
    const int wid = threadIdx.x >> 6;
    const int l = threadIdx.x & 63;
    const int ln = l & 15, g = l >> 4;
    const int ibase = blockIdx.x * 128 + wid * 32;
    const int otile = blockIdx.y * 32;
    const int b = blockIdx.z;

    f32x4 acc[2][2];
    #pragma unroll
    for (int mt = 0; mt < 2; ++mt)
        #pragma unroll
        for (int nt = 0; nt < 2; ++nt) {
            f32x4 z = {0.f, 0.f, 0.f, 0.f};
            acc[mt][nt] = z;
        }

    #pragma unroll
    for (int ks = 0; ks < 16; ++ks) {
        const int c0 = 32 * ks + 8 * g;
        const int cp0 = c0 >> 1;
        f16x8 wf[2];
        #pragma unroll
        for (int mt = 0; mt < 2; ++mt)
            wf[mt] = *reinterpret_cast<const f16x8*>(
                woh + (size_t)(otile + 16 * mt + ln) * HID + c0);
        #pragma unroll
        for (int nt = 0; nt < 2; ++nt) {
            const int pos = ibase + 16 * nt + ln;
            const size_t obase = ((size_t)b * 256 + cp0) * P + pos;
            F8U bh;
            bh.u[0] = oh[obase];
            bh.u[1] = oh[obase + P];
            bh.u[2] = oh[obase + 2 * (size_t)P];
            bh.u[3] = oh[obase + 3 * (size_t)P];
            #pragma unroll
            for (int mt = 0; mt < 2; ++mt)
                acc[mt][nt] = MFMA16(wf[mt], bh.v, acc[mt][nt]);
        }
    }

    #pragma unroll
    for (int mt = 0; mt < 2; ++mt)
        #pragma unroll
        for (int r = 0; r < 4; ++r) {
            int o_ = otile + 16 * mt + 4 * g + r;
            float bv = bo[o_];
            #pragma unroll
            for (int nt = 0; nt < 2; ++nt)
                out[((size_t)b * CQ + o_) * P + ibase + 16 * nt + ln] =
                    acc[mt][nt][r] + bv;
        }
}

extern "C" void kernel_launch(void* const* d_in, const int* in_sizes, int n_in,
                              void* d_out, int out_size, void* d_ws, size_t ws_size,
                              hipStream_t stream) {
    (void)in_sizes; (void)n_in; (void)out_size; (void)ws_size;
    const float* x   = (const float*)d_in[0];
    const float* ctx = (const float*)d_in[1];
    const float* Wq  = (const float*)d_in[2];
    const float* Wk  = (const float*)d_in[3];
    const float* Wv  = (const float*)d_in[4];
    const float* Wo  = (const float*)d_in[5];
    const float* bo  = (const float*)d_in[6];
    float* out = (float*)d_out;

    // Workspace (ushort units). oh (u32[4194304] = 16.8 MB) aliases xh/xl,
    // which are dead before attn writes oh.
    unsigned short* ws = (unsigned short*)d_ws;
    uint32_t* oh         = (uint32_t*)ws;            // 4194304 u32
    unsigned short* xh   = ws;                       // 4194304
    unsigned short* xl   = ws + (size_t)4194304;
    unsigned short* ctxh = ws + (size_t)8388608;     // 2097152
    unsigned short* ctxl = ws + (size_t)10485760;
    unsigned short* qh   = ws + (size_t)16777216;    // 8388608
    unsigned short* ql   = qh + (size_t)8388608;
    unsigned short* kh   = ql + (size_t)8388608;     // 2097152
    unsigned short* kl   = kh + (size_t)2097152;
    unsigned short* vh   = kl + (size_t)2097152;     // 2097152
    unsigned short* woh  = vh + (size_t)2097152;     // 131072
    unsigned short* wqh  = woh + (size_t)131072;     // 131072
    unsigned short* wql  = wqh + (size_t)131072;
    unsigned short* wkh  = wql + (size_t)131072;     // 262144
    unsigned short* wkl  = wkh + (size_t)262144;
    unsigned short* wvh  = wkl + (size_t)262144;
    unsigned short* wvl  = wvh + (size_t)262144;

    dim3 blk(256);
    // 1. weight splits (octet layout)
    split_all<<<dim3(768), blk, 0, stream>>>(
        Wq, Wk, Wv, Wo, wqh, wql, wkh, wkl, wvh, wvl, woh);
    // 2. input transpose-splits (octet layout, x + ctx)
    split_tr<<<dim3(384, 1, BATCH), blk, 0, stream>>>(
        x, ctx, xh, xl, ctxh, ctxl);
    // 3. fused Q/K/V projections (MFMA, coalesced)
    proj_qkv<<<dim3(96, 4, BATCH), blk, 0, stream>>>(
        wqh, wql, wkh, wkl, wvh, wvl, xh, xl, ctxh, ctxl, qh, ql, kh, kl, vh);
    // 4. attention -> oh transposed (clobbers xh/xl — dead by now)
    attn_mfma<<<dim3(HEADS * BATCH, P / 256), blk, 0, stream>>>(
        qh, ql, kh, kl, vh, oh);
    // 5. out = Wo @ O + bo
    out_proj<<<dim3(P / 128, CQ / 32, BATCH), blk, 0, stream>>>(
        woh, oh, bo, out);
}

// Round 13
// 175.533 us; speedup vs baseline: 1.5422x; 1.1394x over previous
//
#include <hip/hip_runtime.h>
#include <math.h>
#include <stdint.h>

// Problem dims (fixed)
#define BATCH 4
#define CQ 256      // x channels
#define P 4096      // query positions (64*64)
#define CC 512      // context channels
#define PC 1024     // kv positions (32*32)
#define HID 512     // HEADS*DIM_HEAD
#define HEADS 8
#define DH 64

// Fold attention scale 1/sqrt(64) * log2(e) into Q so softmax uses exp2.
#define QSCALE 0.180336880111113703f

typedef __attribute__((ext_vector_type(8))) __fp16 f16x8;
typedef __attribute__((ext_vector_type(2))) __fp16 f16x2;
typedef __attribute__((ext_vector_type(4))) float f32x4;
typedef __attribute__((ext_vector_type(4))) unsigned int u32x4;

union H2U { f16x2 h; uint32_t u; };
union F8U { uint32_t u[4]; f16x8 v; };

__device__ __forceinline__ uint32_t pkh(float a, float b) {
    H2U z; z.h = __builtin_amdgcn_cvt_pkrtz(a, b); return z.u;
}
__device__ __forceinline__ f16x2 upk(uint32_t w) { H2U z; z.u = w; return z.h; }
__device__ __forceinline__ void split2(float a, float b, uint32_t& hw, uint32_t& lw) {
    hw = pkh(a, b);
    f16x2 h = upk(hw);
    lw = pkh(a - (float)h[0], b - (float)h[1]);
}

#if __has_builtin(__builtin_amdgcn_exp2f)
#define EXP2(x) __builtin_amdgcn_exp2f(x)
#else
#define EXP2(x) exp2f(x)
#endif

#define MFMA16(a, b, c) __builtin_amdgcn_mfma_f32_16x16x32_f16(a, b, c, 0, 0, 0)

// async global -> LDS, 16B per lane. lds base must be wave-uniform.
__device__ __forceinline__ void gl_lds16(const unsigned short* g, unsigned short* l) {
    __builtin_amdgcn_global_load_lds(
        (const __attribute__((address_space(1))) unsigned int*)g,
        (__attribute__((address_space(3))) unsigned int*)l, 16, 0, 0);
}

// ---------------------------------------------------------------------------
// Split all weights once (float4-vectorized).
// wq/wk/wv -> octet layout [k/8][m][8] hi+lo (wq pre-scaled by QSCALE);
// wo -> linear [o][c] hi only.
// ---------------------------------------------------------------------------
__global__ __launch_bounds__(256) void split_all(
    const float* __restrict__ Wq, const float* __restrict__ Wk,
    const float* __restrict__ Wv, const float* __restrict__ Wo,
    unsigned short* __restrict__ wqh, unsigned short* __restrict__ wql,
    unsigned short* __restrict__ wkh, unsigned short* __restrict__ wkl,
    unsigned short* __restrict__ wvh, unsigned short* __restrict__ wvl,
    unsigned short* __restrict__ woh)
{
    const int bid = blockIdx.x;
    const int t = threadIdx.x;
    const float* src; unsigned short *dh, *dl; int i4; float sc = 1.f; int ksh;
    if (bid < 128)      { src = Wq; dh = wqh; dl = wql; i4 = bid * 256 + t; sc = QSCALE; ksh = 8; }
    else if (bid < 384) { src = Wk; dh = wkh; dl = wkl; i4 = (bid - 128) * 256 + t; ksh = 9; }
    else if (bid < 640) { src = Wv; dh = wvh; dl = wvl; i4 = (bid - 384) * 256 + t; ksh = 9; }
    else                { src = Wo; dh = woh; dl = nullptr; i4 = (bid - 640) * 256 + t; ksh = 0; }
    float4 v = *reinterpret_cast<const float4*>(src + (size_t)i4 * 4);
    uint32_t hw0, hw1, lw0, lw1;
    split2(sc * v.x, sc * v.y, hw0, lw0);
    split2(sc * v.z, sc * v.w, hw1, lw1);
    uint2 hh; hh.x = hw0; hh.y = hw1;
    if (ksh) {
        const int lin = i4 * 4;
        const int m = lin >> ksh;
        const int k = lin & ((1 << ksh) - 1);
        const size_t off = ((size_t)(k >> 3) * HID + m) * 8 + (k & 7);
        *reinterpret_cast<uint2*>(dh + off) = hh;
        uint2 ll; ll.x = lw0; ll.y = lw1;
        *reinterpret_cast<uint2*>(dl + off) = ll;
    } else {
        *reinterpret_cast<uint2*>(dh + (size_t)i4 * 4) = hh;
    }
}

// ---------------------------------------------------------------------------
// Transpose-split both inputs to octet layout [b][k/8][pos][8] fp16 hi/lo.
//   idx < 256: x [b][256][4096];  else: ctx [b][512][1024]
// ---------------------------------------------------------------------------
__global__ __launch_bounds__(256) void split_tr(
    const float* __restrict__ x, const float* __restrict__ ctx,
    unsigned short* __restrict__ xh, unsigned short* __restrict__ xl,
    unsigned short* __restrict__ ch, unsigned short* __restrict__ cl)
{
    const int b = blockIdx.z;
    const int idx = blockIdx.x;
    const float* in; unsigned short *Dh, *Dl; int C, Npos, p0, c0;
    if (idx < 256) {
        in = x; Dh = xh; Dl = xl; C = CQ; Npos = P;
        p0 = (idx & 63) * 64; c0 = (idx >> 6) * 64;
    } else {
        in = ctx; Dh = ch; Dl = cl; C = CC; Npos = PC;
        const int u = idx - 256;
        p0 = (u & 15) * 64; c0 = (u >> 4) * 64;
    }
    const int tid = threadIdx.x;
    const int tx = tid & 15, ty = tid >> 4;
    const float* src = in + (size_t)b * C * Npos;

    __shared__ float Ls[64][65];

    #pragma unroll
    for (int it = 0; it < 4; ++it) {
        const int clr = 16 * it + ty;
        float4 v = *reinterpret_cast<const float4*>(
            &src[(size_t)(c0 + clr) * Npos + p0 + 4 * tx]);
        Ls[clr][4 * tx + 0] = v.x; Ls[clr][4 * tx + 1] = v.y;
        Ls[clr][4 * tx + 2] = v.z; Ls[clr][4 * tx + 3] = v.w;
    }
    __syncthreads();

    // 512 (oct,pos) entries of 16B; wave-uniform octet, lane = pos.
    const int l = tid & 63, wv_ = tid >> 6;
    #pragma unroll
    for (int pass = 0; pass < 2; ++pass) {
        const int oct = pass * 4 + wv_;
        float v0 = Ls[oct * 8 + 0][l], v1 = Ls[oct * 8 + 1][l];
        float v2 = Ls[oct * 8 + 2][l], v3 = Ls[oct * 8 + 3][l];
        float v4 = Ls[oct * 8 + 4][l], v5 = Ls[oct * 8 + 5][l];
        float v6 = Ls[oct * 8 + 6][l], v7 = Ls[oct * 8 + 7][l];
        uint32_t h0, h1, h2, h3, l0, l1, l2, l3;
        split2(v0, v1, h0, l0); split2(v2, v3, h1, l1);
        split2(v4, v5, h2, l2); split2(v6, v7, h3, l3);
        const size_t base =
            ((size_t)(b * (C >> 3) + (c0 >> 3) + oct) * Npos + p0 + l) * 8;
        u32x4 hh; hh[0] = h0; hh[1] = h1; hh[2] = h2; hh[3] = h3;
        u32x4 ll; ll[0] = l0; ll[1] = l1; ll[2] = l2; ll[3] = l3;
        *reinterpret_cast<u32x4*>(Dh + base) = hh;
        *reinterpret_cast<u32x4*>(Dl + base) = ll;
    }
}

// ---------------------------------------------------------------------------
// Fused Q + K + V projections, 3-term split-fp16 MFMA, coalesced octet loads.
// blockIdx.x < 64: Q; in [64,96): K (u>>4==0) / V (==1).
// ---------------------------------------------------------------------------
__global__ __launch_bounds__(256) void proj_qkv(
    const unsigned short* __restrict__ wqh_, const unsigned short* __restrict__ wql_,
    const unsigned short* __restrict__ wkh_, const unsigned short* __restrict__ wkl_,
    const unsigned short* __restrict__ wvh_, const unsigned short* __restrict__ wvl_,
    const unsigned short* __restrict__ xh_, const unsigned short* __restrict__ xl_,
    const unsigned short* __restrict__ ch_, const unsigned short* __restrict__ cl_,
    unsigned short* __restrict__ qh_, unsigned short* __restrict__ ql_,
    unsigned short* __restrict__ kh_, unsigned short* __restrict__ kl_,
    unsigned short* __restrict__ vh_)
{
    const int b = blockIdx.z;
    const int bx = blockIdx.x;
    const int wid = threadIdx.x >> 6;
    const int l = threadIdx.x & 63;
    const int ln = l & 15, g = l >> 4;
    const int mb = blockIdx.y * 128 + 64 * (wid & 1);

    f32x4 acc[4][2];
    #pragma unroll
    for (int mt = 0; mt < 4; ++mt)
        #pragma unroll
        for (int nt = 0; nt < 2; ++nt) {
            f32x4 z = {0.f, 0.f, 0.f, 0.f};
            acc[mt][nt] = z;
        }

    int mode;        // 0=Q, 1=K, 2=V
    int nb;
    if (bx < 64) {
        mode = 0;
        nb = bx * 64 + 32 * (wid >> 1);
        #pragma unroll 4
        for (int k0 = 0; k0 < CQ; k0 += 32) {
            const int kq = (k0 >> 3) + g;
            f16x8 ah[4], al[4], bh[2], bl[2];
            #pragma unroll
            for (int mt = 0; mt < 4; ++mt) {
                const size_t off = ((size_t)kq * HID + mb + 16 * mt + ln) * 8;
                ah[mt] = *reinterpret_cast<const f16x8*>(wqh_ + off);
                al[mt] = *reinterpret_cast<const f16x8*>(wql_ + off);
            }
            #pragma unroll
            for (int nt = 0; nt < 2; ++nt) {
                const size_t off = ((size_t)(b * 32 + kq) * P + nb + 16 * nt + ln) * 8;
                bh[nt] = *reinterpret_cast<const f16x8*>(xh_ + off);
                bl[nt] = *reinterpret_cast<const f16x8*>(xl_ + off);
            }
            #pragma unroll
            for (int mt = 0; mt < 4; ++mt)
                #pragma unroll
                for (int nt = 0; nt < 2; ++nt) {
                    acc[mt][nt] = MFMA16(ah[mt], bh[nt], acc[mt][nt]);
                    acc[mt][nt] = MFMA16(ah[mt], bl[nt], acc[mt][nt]);
                    acc[mt][nt] = MFMA16(al[mt], bh[nt], acc[mt][nt]);
                }
        }
    } else {
        const int u = bx - 64;
        mode = 1 + (u >> 4);
        nb = (u & 15) * 64 + 32 * (wid >> 1);
        const unsigned short* Ah = (mode == 2) ? wvh_ : wkh_;
        const unsigned short* Al = (mode == 2) ? wvl_ : wkl_;
        #pragma unroll 4
        for (int k0 = 0; k0 < CC; k0 += 32) {
            const int kq = (k0 >> 3) + g;
            f16x8 ah[4], al[4], bh[2], bl[2];
            #pragma unroll
            for (int mt = 0; mt < 4; ++mt) {
                const size_t off = ((size_t)kq * HID + mb + 16 * mt + ln) * 8;
                ah[mt] = *reinterpret_cast<const f16x8*>(Ah + off);
                al[mt] = *reinterpret_cast<const f16x8*>(Al + off);
            }
            #pragma unroll
            for (int nt = 0; nt < 2; ++nt) {
                const size_t off = ((size_t)(b * 64 + kq) * PC + nb + 16 * nt + ln) * 8;
                bh[nt] = *reinterpret_cast<const f16x8*>(ch_ + off);
                bl[nt] = *reinterpret_cast<const f16x8*>(cl_ + off);
            }
            #pragma unroll
            for (int mt = 0; mt < 4; ++mt)
                #pragma unroll
                for (int nt = 0; nt < 2; ++nt) {
                    acc[mt][nt] = MFMA16(ah[mt], bh[nt], acc[mt][nt]);
                    acc[mt][nt] = MFMA16(ah[mt], bl[nt], acc[mt][nt]);
                    acc[mt][nt] = MFMA16(al[mt], bh[nt], acc[mt][nt]);
                }
        }
    }

    if (mode == 0) {
        #pragma unroll
        for (int mt = 0; mt < 4; ++mt) {
            const int m0 = mb + 16 * mt + 4 * g;
            const int h = m0 >> 6, cl2 = m0 & 63;
            #pragma unroll
            for (int nt = 0; nt < 2; ++nt) {
                const int pos = nb + 16 * nt + ln;
                uint32_t hw0, hw1, lw0, lw1;
                split2(acc[mt][nt][0], acc[mt][nt][1], hw0, lw0);
                split2(acc[mt][nt][2], acc[mt][nt][3], hw1, lw1);
                const size_t base = (((size_t)b * HEADS + h) * P + pos) * 64 + cl2;
                uint2 hh; hh.x = hw0; hh.y = hw1;
                uint2 ll; ll.x = lw0; ll.y = lw1;
                *reinterpret_cast<uint2*>(qh_ + base) = hh;
                *reinterpret_cast<uint2*>(ql_ + base) = ll;
            }
        }
    } else if (mode == 1) {
        #pragma unroll
        for (int mt = 0; mt < 4; ++mt) {
            const int m0 = mb + 16 * mt + 4 * g;
            const int h = m0 >> 6, cl2 = m0 & 63;
            #pragma unroll
            for (int nt = 0; nt < 2; ++nt) {
                const int pos = nb + 16 * nt + ln;
                uint32_t hw0, hw1, lw0, lw1;
                split2(acc[mt][nt][0], acc[mt][nt][1], hw0, lw0);
                split2(acc[mt][nt][2], acc[mt][nt][3], hw1, lw1);
                const size_t base = (((size_t)b * HEADS + h) * PC + pos) * 64 + cl2;
                uint2 hh; hh.x = hw0; hh.y = hw1;
                uint2 ll; ll.x = lw0; ll.y = lw1;
                *reinterpret_cast<uint2*>(kh_ + base) = hh;
                *reinterpret_cast<uint2*>(kl_ + base) = ll;
            }
        }
    } else {
        #pragma unroll
        for (int mt = 0; mt < 4; ++mt) {
            const int m0 = mb + 16 * mt + 4 * g;   // V channel 0..511
            #pragma unroll
            for (int nt = 0; nt < 2; ++nt) {
                const int pos = nb + 16 * nt + ln;
                #pragma unroll
                for (int r = 0; r < 4; ++r) {
                    unsigned short hv =
                        (unsigned short)(pkh(acc[mt][nt][r], 0.f) & 0xffffu);
                    vh_[((size_t)b * HID + m0 + r) * PC + pos] = hv;
                }
            }
        }
    }
}

// ---------------------------------------------------------------------------
// Flash attention, fixed-max softmax (m == 0; P = exp2(s), bounded by
// ~2^9 << fp16 max — see analysis). No max-reduce, no rescale, no skip.
// l accumulated per-lane, reduced once in the epilogue.
// Core MFMA/LDS structure identical to R9-R12 (verified).
// ---------------------------------------------------------------------------
#define NIN 4
#define JBLK 32
#define NJT (PC / JBLK)

__global__ __launch_bounds__(256, 2) void attn_mfma(
    const unsigned short* __restrict__ qh, const unsigned short* __restrict__ ql,
    const unsigned short* __restrict__ kh, const unsigned short* __restrict__ kl,
    const unsigned short* __restrict__ vh,
    uint32_t* __restrict__ oh)
{
    const int wid = threadIdx.x >> 6;
    const int l = threadIdx.x & 63;
    const int ln = l & 15, g = l >> 4;
    const int rx = ln & 7;
    const int hb = blockIdx.x;                 // (h, b) composite
    const int h = hb & 7, b = hb >> 3;
    const int i0 = (blockIdx.y * 4 + wid) * 64;

    const size_t qbase = (size_t)(b * HEADS + h) * P * 64;
    const size_t kbase = (size_t)(b * HEADS + h) * PC * 64;
    const size_t vbase = (size_t)(b * HID + h * DH) * PC;

    __shared__ unsigned short smem[2][6144];

    f16x8 qf[NIN][2][2];
    #pragma unroll
    for (int in_ = 0; in_ < NIN; ++in_) {
        const size_t qrow = qbase + (size_t)(i0 + 16 * in_ + ln) * 64 + 8 * g;
        #pragma unroll
        for (int ks = 0; ks < 2; ++ks) {
            qf[in_][ks][0] = *reinterpret_cast<const f16x8*>(qh + qrow + 32 * ks);
            qf[in_][ks][1] = *reinterpret_cast<const f16x8*>(ql + qrow + 32 * ks);
        }
    }

    f32x4 acc[4][NIN];
    #pragma unroll
    for (int cm = 0; cm < 4; ++cm)
        #pragma unroll
        for (int in_ = 0; in_ < NIN; ++in_) {
            f32x4 z = {0.f, 0.f, 0.f, 0.f};
            acc[cm][in_] = z;
        }
    float lsum[NIN];
    #pragma unroll
    for (int in_ = 0; in_ < NIN; ++in_) lsum[in_] = 0.f;

    const int idx0 = ln + 16 * (2 * (g & 1));
    const int idx1 = idx0 + 16;
    const bool topTile = (g & 2) != 0;

    auto stage = [&](int buf, int jt) {
        const int j0 = jt * JBLK;
        #pragma unroll
        for (int t = 0; t < 3; ++t) {
            const int s = wid * 3 + t;
            unsigned short* lbase = &smem[buf][s * 512];
            const int i = (s & 3) * 64 + l;
            const int row = i >> 3, p = i & 7;
            const int slog = p ^ (row & 7);
            const unsigned short* src;
            if (s < 4) {
                src = kh + kbase + (size_t)(j0 + row) * 64 + 8 * slog;
            } else if (s < 8) {
                src = kl + kbase + (size_t)(j0 + row) * 64 + 8 * slog;
            } else {
                const int c = 2 * row + (slog >> 2);
                src = vh + vbase + (size_t)c * PC + j0 + 8 * (slog & 3);
            }
            gl_lds16(src, lbase);
        }
    };

    stage(0, 0);
    __syncthreads();

    for (int jt = 0; jt < NJT; ++jt) {
        const int cur = jt & 1;
        if (jt + 1 < NJT) stage(cur ^ 1, jt + 1);
        const unsigned short* sm = &smem[cur][0];

        f16x8 kf[2][2][2];
        #pragma unroll
        for (int jm = 0; jm < 2; ++jm)
            #pragma unroll
            for (int ks = 0; ks < 2; ++ks) {
                const int base = (16 * jm + ln) * 64 + 8 * ((4 * ks + g) ^ rx);
                kf[jm][ks][0] = *reinterpret_cast<const f16x8*>(sm + base);
                kf[jm][ks][1] = *reinterpret_cast<const f16x8*>(sm + 2048 + base);
            }
        f16x8 vf[4];
        #pragma unroll
        for (int cm = 0; cm < 4; ++cm) {
            const int vaddr = 4096 + (8 * cm + (ln >> 1)) * 64 +
                              8 * ((4 * (ln & 1) + g) ^ (ln >> 1));
            vf[cm] = *reinterpret_cast<const f16x8*>(sm + vaddr);
        }

        f32x4 s[2][NIN];
        #pragma unroll
        for (int jm = 0; jm < 2; ++jm)
            #pragma unroll
            for (int in_ = 0; in_ < NIN; ++in_) {
                f32x4 z = {0.f, 0.f, 0.f, 0.f};
                s[jm][in_] = z;
            }
        __builtin_amdgcn_s_setprio(1);
        #pragma unroll
        for (int jm = 0; jm < 2; ++jm)
            #pragma unroll
            for (int ks = 0; ks < 2; ++ks)
                #pragma unroll
                for (int in_ = 0; in_ < NIN; ++in_) {
                    s[jm][in_] = MFMA16(kf[jm][ks][0], qf[in_][ks][0], s[jm][in_]);
                    s[jm][in_] = MFMA16(kf[jm][ks][0], qf[in_][ks][1], s[jm][in_]);
                    s[jm][in_] = MFMA16(kf[jm][ks][1], qf[in_][ks][0], s[jm][in_]);
                }
        __builtin_amdgcn_s_setprio(0);

        // ---- fixed-max softmax: P = exp2(s); lsum per-lane partial ----
        #pragma unroll
        for (int in_ = 0; in_ < NIN; ++in_) {
            float ls = 0.f;
            #pragma unroll
            for (int jm = 0; jm < 2; ++jm)
                #pragma unroll
                for (int r = 0; r < 4; ++r) {
                    float p = EXP2(s[jm][in_][r]);
                    s[jm][in_][r] = p; ls += p;
                }
            lsum[in_] += ls;

            int w00 = (int)pkh(s[0][in_][0], s[0][in_][1]);
            int w01 = (int)pkh(s[0][in_][2], s[0][in_][3]);
            int w10 = (int)pkh(s[1][in_][0], s[1][in_][1]);
            int w11 = (int)pkh(s[1][in_][2], s[1][in_][3]);

            int a0 = __shfl(w00, idx0, 64), a1 = __shfl(w01, idx0, 64);
            int a2 = __shfl(w00, idx1, 64), a3 = __shfl(w01, idx1, 64);
            int b0 = __shfl(w10, idx0, 64), b1 = __shfl(w11, idx0, 64);
            int b2 = __shfl(w10, idx1, 64), b3 = __shfl(w11, idx1, 64);
            F8U fu;
            fu.u[0] = (uint32_t)(topTile ? b0 : a0);
            fu.u[1] = (uint32_t)(topTile ? b1 : a1);
            fu.u[2] = (uint32_t)(topTile ? b2 : a2);
            fu.u[3] = (uint32_t)(topTile ? b3 : a3);

            __builtin_amdgcn_s_setprio(1);
            #pragma unroll
            for (int cm = 0; cm < 4; ++cm)
                acc[cm][in_] = MFMA16(vf[cm], fu.v, acc[cm][in_]);
            __builtin_amdgcn_s_setprio(0);
        }

        __syncthreads();
    }

    // epilogue: reduce lsum across g-groups, then O/l -> fp16 hi,
    // transposed [b][cp][pos], coalesced 4B stores.
    #pragma unroll
    for (int in_ = 0; in_ < NIN; ++in_) {
        float lt = lsum[in_];
        lt += __shfl_xor(lt, 16, 64);
        lt += __shfl_xor(lt, 32, 64);
        float inv = 1.0f / lt;
        int i = i0 + 16 * in_ + ln;
        #pragma unroll
        for (int cm = 0; cm < 4; ++cm) {
            f32x4 o4 = acc[cm][in_] * inv;
            const int cp = 32 * h + 8 * cm + 2 * g;
            const size_t idx = ((size_t)b * 256 + cp) * P + i;
            oh[idx] = pkh(o4[0], o4[1]);
            oh[idx + P] = pkh(o4[2], o4[3]);
        }
    }
}

// ---------------------------------------------------------------------------
// Output projection: out = Wo_h @ O_h + bo (1-term fp16 MFMA), coalesced
// B-loads from transposed oh [b][cp][pos].
// ---------------------------------------------------------------------------
__global__ __launch_bounds__(256, 4) void out_proj(
    const unsigned short* __restrict__ woh, const uint32_t* __restrict__ oh,
    const float* __restrict__ bo, float* __restrict__ out)
{
    const int wid = threadIdx.x >> 6;
    const int l = threadIdx.x & 63;
    const int ln = l & 15, g = l >> 4;
    const int ibase = blockIdx.x * 128 + wid * 32;
    const int otile = blockIdx.y * 32;
    const int b = blockIdx.z;

    f32x4 acc[2][2];
    #pragma unroll
    for (int mt = 0; mt < 2; ++mt)
        #pragma unroll
        for (int nt = 0; nt < 2; ++nt) {
            f32x4 z = {0.f, 0.f, 0.f, 0.f};
            acc[mt][nt] = z;
        }

    #pragma unroll
    for (int ks = 0; ks < 16; ++ks) {
        const int c0 = 32 * ks + 8 * g;
        const int cp0 = c0 >> 1;
        f16x8 wf[2];
        #pragma unroll
        for (int mt = 0; mt < 2; ++mt)
            wf[mt] = *reinterpret_cast<const f16x8*>(
                woh + (size_t)(otile + 16 * mt + ln) * HID + c0);
        #pragma unroll
        for (int nt = 0; nt < 2; ++nt) {
            const int pos = ibase + 16 * nt + ln;
            const size_t obase = ((size_t)b * 256 + cp0) * P + pos;
            F8U bh;
            bh.u[0] = oh[obase];
            bh.u[1] = oh[obase + P];
            bh.u[2] = oh[obase + 2 * (size_t)P];
            bh.u[3] = oh[obase + 3 * (size_t)P];
            #pragma unroll
            for (int mt = 0; mt < 2; ++mt)
                acc[mt][nt] = MFMA16(wf[mt], bh.v, acc[mt][nt]);
        }
    }

    #pragma unroll
    for (int mt = 0; mt < 2; ++mt)
        #pragma unroll
        for (int r = 0; r < 4; ++r) {
            int o_ = otile + 16 * mt + 4 * g + r;
            float bv = bo[o_];
            #pragma unroll
            for (int nt = 0; nt < 2; ++nt)
                out[((size_t)b * CQ + o_) * P + ibase + 16 * nt + ln] =
                    acc[mt][nt][r] + bv;
        }
}

extern "C" void kernel_launch(void* const* d_in, const int* in_sizes, int n_in,
                              void* d_out, int out_size, void* d_ws, size_t ws_size,
                              hipStream_t stream) {
    (void)in_sizes; (void)n_in; (void)out_size; (void)ws_size;
    const float* x   = (const float*)d_in[0];
    const float* ctx = (const float*)d_in[1];
    const float* Wq  = (const float*)d_in[2];
    const float* Wk  = (const float*)d_in[3];
    const float* Wv  = (const float*)d_in[4];
    const float* Wo  = (const float*)d_in[5];
    const float* bo  = (const float*)d_in[6];
    float* out = (float*)d_out;

    // Workspace (ushort units). oh (u32[4194304] = 16.8 MB) aliases xh/xl,
    // which are dead before attn writes oh.
    unsigned short* ws = (unsigned short*)d_ws;
    uint32_t* oh         = (uint32_t*)ws;            // 4194304 u32
    unsigned short* xh   = ws;                       // 4194304
    unsigned short* xl   = ws + (size_t)4194304;
    unsigned short* ctxh = ws + (size_t)8388608;     // 2097152
    unsigned short* ctxl = ws + (size_t)10485760;
    unsigned short* qh   = ws + (size_t)16777216;    // 8388608
    unsigned short* ql   = qh + (size_t)8388608;
    unsigned short* kh   = ql + (size_t)8388608;     // 2097152
    unsigned short* kl   = kh + (size_t)2097152;
    unsigned short* vh   = kl + (size_t)2097152;     // 2097152
    unsigned short* woh  = vh + (size_t)2097152;     // 131072
    unsigned short* wqh  = woh + (size_t)131072;     // 131072
    unsigned short* wql  = wqh + (size_t)131072;
    unsigned short* wkh  = wql + (size_t)131072;     // 262144
    unsigned short* wkl  = wkh + (size_t)262144;
    unsigned short* wvh  = wkl + (size_t)262144;
    unsigned short* wvl  = wvh + (size_t)262144;

    dim3 blk(256);
    // 1. weight splits (octet layout)
    split_all<<<dim3(768), blk, 0, stream>>>(
        Wq, Wk, Wv, Wo, wqh, wql, wkh, wkl, wvh, wvl, woh);
    // 2. input transpose-splits (octet layout, x + ctx)
    split_tr<<<dim3(384, 1, BATCH), blk, 0, stream>>>(
        x, ctx, xh, xl, ctxh, ctxl);
    // 3. fused Q/K/V projections (MFMA, coalesced)
    proj_qkv<<<dim3(96, 4, BATCH), blk, 0, stream>>>(
        wqh, wql, wkh, wkl, wvh, wvl, xh, xl, ctxh, ctxl, qh, ql, kh, kl, vh);
    // 4. attention -> oh transposed (clobbers xh/xl — dead by now)
    attn_mfma<<<dim3(HEADS * BATCH, P / 256), blk, 0, stream>>>(
        qh, ql, kh, kl, vh, oh);
    // 5. out = Wo @ O + bo
    out_proj<<<dim3(P / 128, CQ / 32, BATCH), blk, 0, stream>>>(
        woh, oh, bo, out);
}

// Round 14
// 129.005 us; speedup vs baseline: 2.0984x; 1.3607x over previous
//
#include <hip/hip_runtime.h>
#include <math.h>
#include <stdint.h>

// Problem dims (fixed)
#define BATCH 4
#define CQ 256      // x channels
#define P 4096      // query positions (64*64)
#define CC 512      // context channels
#define PC 1024     // kv positions (32*32)
#define HID 512     // HEADS*DIM_HEAD
#define HEADS 8
#define DH 64

// Fold attention scale 1/sqrt(64) * log2(e) into Q so softmax uses exp2.
#define QSCALE 0.180336880111113703f

typedef __attribute__((ext_vector_type(8))) __fp16 f16x8;
typedef __attribute__((ext_vector_type(2))) __fp16 f16x2;
typedef __attribute__((ext_vector_type(4))) float f32x4;
typedef __attribute__((ext_vector_type(4))) unsigned int u32x4;

union H2U { f16x2 h; uint32_t u; };
union F8U { uint32_t u[4]; f16x8 v; };

__device__ __forceinline__ uint32_t pkh(float a, float b) {
    H2U z; z.h = __builtin_amdgcn_cvt_pkrtz(a, b); return z.u;
}
__device__ __forceinline__ f16x2 upk(uint32_t w) { H2U z; z.u = w; return z.h; }
__device__ __forceinline__ void split2(float a, float b, uint32_t& hw, uint32_t& lw) {
    hw = pkh(a, b);
    f16x2 h = upk(hw);
    lw = pkh(a - (float)h[0], b - (float)h[1]);
}

#if __has_builtin(__builtin_amdgcn_exp2f)
#define EXP2(x) __builtin_amdgcn_exp2f(x)
#else
#define EXP2(x) exp2f(x)
#endif

#define MFMA16(a, b, c) __builtin_amdgcn_mfma_f32_16x16x32_f16(a, b, c, 0, 0, 0)

// async global -> LDS, 16B per lane. lds base must be wave-uniform.
__device__ __forceinline__ void gl_lds16(const unsigned short* g, unsigned short* l) {
    __builtin_amdgcn_global_load_lds(
        (const __attribute__((address_space(1))) unsigned int*)g,
        (__attribute__((address_space(3))) unsigned int*)l, 16, 0, 0);
}

// ---------------------------------------------------------------------------
// Split weights, fp16 HI only (float4-vectorized).
// wq/wk/wv -> octet layout [k/8][m][8] (wq pre-scaled by QSCALE);
// wo -> linear [o][c].
// ---------------------------------------------------------------------------
__global__ __launch_bounds__(256) void split_all(
    const float* __restrict__ Wq, const float* __restrict__ Wk,
    const float* __restrict__ Wv, const float* __restrict__ Wo,
    unsigned short* __restrict__ wqh, unsigned short* __restrict__ wkh,
    unsigned short* __restrict__ wvh, unsigned short* __restrict__ woh)
{
    const int bid = blockIdx.x;
    const int t = threadIdx.x;
    const float* src; unsigned short* dh; int i4; float sc = 1.f; int ksh;
    if (bid < 128)      { src = Wq; dh = wqh; i4 = bid * 256 + t; sc = QSCALE; ksh = 8; }
    else if (bid < 384) { src = Wk; dh = wkh; i4 = (bid - 128) * 256 + t; ksh = 9; }
    else if (bid < 640) { src = Wv; dh = wvh; i4 = (bid - 384) * 256 + t; ksh = 9; }
    else                { src = Wo; dh = woh; i4 = (bid - 640) * 256 + t; ksh = 0; }
    float4 v = *reinterpret_cast<const float4*>(src + (size_t)i4 * 4);
    uint2 hh;
    hh.x = pkh(sc * v.x, sc * v.y);
    hh.y = pkh(sc * v.z, sc * v.w);
    if (ksh) {
        const int lin = i4 * 4;
        const int m = lin >> ksh;
        const int k = lin & ((1 << ksh) - 1);
        const size_t off = ((size_t)(k >> 3) * HID + m) * 8 + (k & 7);
        *reinterpret_cast<uint2*>(dh + off) = hh;
    } else {
        *reinterpret_cast<uint2*>(dh + (size_t)i4 * 4) = hh;
    }
}

// ---------------------------------------------------------------------------
// Fused Q + K + V projections, 1-term fp16 MFMA (Wh * Xh), reading RAW fp32
// inputs (8 coalesced dword loads + pack per B-frag — no split_tr pass).
// blockIdx.x < 64: Q; in [64,96): K (u>>4==0) / V (==1).
// Q out: qh/ql [b][h][pos][64] (hi+lo from fp32 acc); K: kh only; V: vh only.
// ---------------------------------------------------------------------------
__global__ __launch_bounds__(256) void proj_qkv(
    const unsigned short* __restrict__ wqh_, const unsigned short* __restrict__ wkh_,
    const unsigned short* __restrict__ wvh_,
    const float* __restrict__ x_, const float* __restrict__ ctx_,
    unsigned short* __restrict__ qh_, unsigned short* __restrict__ ql_,
    unsigned short* __restrict__ kh_, unsigned short* __restrict__ vh_)
{
    const int b = blockIdx.z;
    const int bx = blockIdx.x;
    const int wid = threadIdx.x >> 6;
    const int l = threadIdx.x & 63;
    const int ln = l & 15, g = l >> 4;
    const int mb = blockIdx.y * 128 + 64 * (wid & 1);

    f32x4 acc[4][2];
    #pragma unroll
    for (int mt = 0; mt < 4; ++mt)
        #pragma unroll
        for (int nt = 0; nt < 2; ++nt) {
            f32x4 z = {0.f, 0.f, 0.f, 0.f};
            acc[mt][nt] = z;
        }

    int mode;        // 0=Q, 1=K, 2=V
    int nb;
    if (bx < 64) {
        mode = 0;
        nb = bx * 64 + 32 * (wid >> 1);
        const float* xb = x_ + (size_t)b * CQ * P;
        #pragma unroll 2
        for (int k0 = 0; k0 < CQ; k0 += 32) {
            const int kq = (k0 >> 3) + g;
            f16x8 ah[4];
            #pragma unroll
            for (int mt = 0; mt < 4; ++mt)
                ah[mt] = *reinterpret_cast<const f16x8*>(
                    wqh_ + ((size_t)kq * HID + mb + 16 * mt + ln) * 8);
            #pragma unroll
            for (int nt = 0; nt < 2; ++nt) {
                const int pos = nb + 16 * nt + ln;
                float v0 = xb[(size_t)(8 * kq + 0) * P + pos];
                float v1 = xb[(size_t)(8 * kq + 1) * P + pos];
                float v2 = xb[(size_t)(8 * kq + 2) * P + pos];
                float v3 = xb[(size_t)(8 * kq + 3) * P + pos];
                float v4 = xb[(size_t)(8 * kq + 4) * P + pos];
                float v5 = xb[(size_t)(8 * kq + 5) * P + pos];
                float v6 = xb[(size_t)(8 * kq + 6) * P + pos];
                float v7 = xb[(size_t)(8 * kq + 7) * P + pos];
                F8U bh;
                bh.u[0] = pkh(v0, v1); bh.u[1] = pkh(v2, v3);
                bh.u[2] = pkh(v4, v5); bh.u[3] = pkh(v6, v7);
                #pragma unroll
                for (int mt = 0; mt < 4; ++mt)
                    acc[mt][nt] = MFMA16(ah[mt], bh.v, acc[mt][nt]);
            }
        }
    } else {
        const int u = bx - 64;
        mode = 1 + (u >> 4);
        nb = (u & 15) * 64 + 32 * (wid >> 1);
        const unsigned short* Ah = (mode == 2) ? wvh_ : wkh_;
        const float* cb = ctx_ + (size_t)b * CC * PC;
        #pragma unroll 2
        for (int k0 = 0; k0 < CC; k0 += 32) {
            const int kq = (k0 >> 3) + g;
            f16x8 ah[4];
            #pragma unroll
            for (int mt = 0; mt < 4; ++mt)
                ah[mt] = *reinterpret_cast<const f16x8*>(
                    Ah + ((size_t)kq * HID + mb + 16 * mt + ln) * 8);
            #pragma unroll
            for (int nt = 0; nt < 2; ++nt) {
                const int pos = nb + 16 * nt + ln;
                float v0 = cb[(size_t)(8 * kq + 0) * PC + pos];
                float v1 = cb[(size_t)(8 * kq + 1) * PC + pos];
                float v2 = cb[(size_t)(8 * kq + 2) * PC + pos];
                float v3 = cb[(size_t)(8 * kq + 3) * PC + pos];
                float v4 = cb[(size_t)(8 * kq + 4) * PC + pos];
                float v5 = cb[(size_t)(8 * kq + 5) * PC + pos];
                float v6 = cb[(size_t)(8 * kq + 6) * PC + pos];
                float v7 = cb[(size_t)(8 * kq + 7) * PC + pos];
                F8U bh;
                bh.u[0] = pkh(v0, v1); bh.u[1] = pkh(v2, v3);
                bh.u[2] = pkh(v4, v5); bh.u[3] = pkh(v6, v7);
                #pragma unroll
                for (int mt = 0; mt < 4; ++mt)
                    acc[mt][nt] = MFMA16(ah[mt], bh.v, acc[mt][nt]);
            }
        }
    }

    if (mode == 0) {
        #pragma unroll
        for (int mt = 0; mt < 4; ++mt) {
            const int m0 = mb + 16 * mt + 4 * g;
            const int h = m0 >> 6, cl2 = m0 & 63;
            #pragma unroll
            for (int nt = 0; nt < 2; ++nt) {
                const int pos = nb + 16 * nt + ln;
                uint32_t hw0, hw1, lw0, lw1;
                split2(acc[mt][nt][0], acc[mt][nt][1], hw0, lw0);
                split2(acc[mt][nt][2], acc[mt][nt][3], hw1, lw1);
                const size_t base = (((size_t)b * HEADS + h) * P + pos) * 64 + cl2;
                uint2 hh; hh.x = hw0; hh.y = hw1;
                uint2 ll; ll.x = lw0; ll.y = lw1;
                *reinterpret_cast<uint2*>(qh_ + base) = hh;
                *reinterpret_cast<uint2*>(ql_ + base) = ll;
            }
        }
    } else if (mode == 1) {
        #pragma unroll
        for (int mt = 0; mt < 4; ++mt) {
            const int m0 = mb + 16 * mt + 4 * g;
            const int h = m0 >> 6, cl2 = m0 & 63;
            #pragma unroll
            for (int nt = 0; nt < 2; ++nt) {
                const int pos = nb + 16 * nt + ln;
                uint2 hh;
                hh.x = pkh(acc[mt][nt][0], acc[mt][nt][1]);
                hh.y = pkh(acc[mt][nt][2], acc[mt][nt][3]);
                const size_t base = (((size_t)b * HEADS + h) * PC + pos) * 64 + cl2;
                *reinterpret_cast<uint2*>(kh_ + base) = hh;
            }
        }
    } else {
        #pragma unroll
        for (int mt = 0; mt < 4; ++mt) {
            const int m0 = mb + 16 * mt + 4 * g;   // V channel 0..511
            #pragma unroll
            for (int nt = 0; nt < 2; ++nt) {
                const int pos = nb + 16 * nt + ln;
                #pragma unroll
                for (int r = 0; r < 4; ++r) {
                    unsigned short hv =
                        (unsigned short)(pkh(acc[mt][nt][r], 0.f) & 0xffffu);
                    vh_[((size_t)b * HID + m0 + r) * PC + pos] = hv;
                }
            }
        }
    }
}

// ---------------------------------------------------------------------------
// Flash attention, fixed-max softmax, 2-term S (kh*qh + kh*ql — K-lo dropped),
// 1-term PV. LDS per buf: Kh 32x64 (4KB... 2048 hw) + V 2048 hw = 8KB, dbuf.
// Core fragment/swizzle addressing identical to R9-R13 (verified), minus Kl.
// ---------------------------------------------------------------------------
#define NIN 4
#define JBLK 32
#define NJT (PC / JBLK)

__global__ __launch_bounds__(256, 2) void attn_mfma(
    const unsigned short* __restrict__ qh, const unsigned short* __restrict__ ql,
    const unsigned short* __restrict__ kh,
    const unsigned short* __restrict__ vh,
    uint32_t* __restrict__ oh)
{
    const int wid = threadIdx.x >> 6;
    const int l = threadIdx.x & 63;
    const int ln = l & 15, g = l >> 4;
    const int rx = ln & 7;
    const int hb = blockIdx.x;                 // (h, b) composite
    const int h = hb & 7, b = hb >> 3;
    const int i0 = (blockIdx.y * 4 + wid) * 64;

    const size_t qbase = (size_t)(b * HEADS + h) * P * 64;
    const size_t kbase = (size_t)(b * HEADS + h) * PC * 64;
    const size_t vbase = (size_t)(b * HID + h * DH) * PC;

    // per buf (4096 hw = 8KB): [0,2048) Kh 32rows x 8slots | [2048,4096) Vh
    __shared__ unsigned short smem[2][4096];

    f16x8 qf[NIN][2][2];
    #pragma unroll
    for (int in_ = 0; in_ < NIN; ++in_) {
        const size_t qrow = qbase + (size_t)(i0 + 16 * in_ + ln) * 64 + 8 * g;
        #pragma unroll
        for (int ks = 0; ks < 2; ++ks) {
            qf[in_][ks][0] = *reinterpret_cast<const f16x8*>(qh + qrow + 32 * ks);
            qf[in_][ks][1] = *reinterpret_cast<const f16x8*>(ql + qrow + 32 * ks);
        }
    }

    f32x4 acc[4][NIN];
    #pragma unroll
    for (int cm = 0; cm < 4; ++cm)
        #pragma unroll
        for (int in_ = 0; in_ < NIN; ++in_) {
            f32x4 z = {0.f, 0.f, 0.f, 0.f};
            acc[cm][in_] = z;
        }
    float lsum[NIN];
    #pragma unroll
    for (int in_ = 0; in_ < NIN; ++in_) lsum[in_] = 0.f;

    const int idx0 = ln + 16 * (2 * (g & 1));
    const int idx1 = idx0 + 16;
    const bool topTile = (g & 2) != 0;

    // staging: 8 segs of 1KB; wave stages segs wid*2, wid*2+1
    auto stage = [&](int buf, int jt) {
        const int j0 = jt * JBLK;
        #pragma unroll
        for (int t = 0; t < 2; ++t) {
            const int s = wid * 2 + t;
            unsigned short* lbase = &smem[buf][s * 512];
            const int i = (s & 3) * 64 + l;
            const int row = i >> 3, p = i & 7;
            const int slog = p ^ (row & 7);
            const unsigned short* src;
            if (s < 4) {
                src = kh + kbase + (size_t)(j0 + row) * 64 + 8 * slog;
            } else {
                const int c = 2 * row + (slog >> 2);
                src = vh + vbase + (size_t)c * PC + j0 + 8 * (slog & 3);
            }
            gl_lds16(src, lbase);
        }
    };

    stage(0, 0);
    __syncthreads();

    for (int jt = 0; jt < NJT; ++jt) {
        const int cur = jt & 1;
        if (jt + 1 < NJT) stage(cur ^ 1, jt + 1);
        const unsigned short* sm = &smem[cur][0];

        f16x8 kf[2][2];
        #pragma unroll
        for (int jm = 0; jm < 2; ++jm)
            #pragma unroll
            for (int ks = 0; ks < 2; ++ks) {
                const int base = (16 * jm + ln) * 64 + 8 * ((4 * ks + g) ^ rx);
                kf[jm][ks] = *reinterpret_cast<const f16x8*>(sm + base);
            }
        f16x8 vf[4];
        #pragma unroll
        for (int cm = 0; cm < 4; ++cm) {
            const int vaddr = 2048 + (8 * cm + (ln >> 1)) * 64 +
                              8 * ((4 * (ln & 1) + g) ^ (ln >> 1));
            vf[cm] = *reinterpret_cast<const f16x8*>(sm + vaddr);
        }

        f32x4 s[2][NIN];
        #pragma unroll
        for (int jm = 0; jm < 2; ++jm)
            #pragma unroll
            for (int in_ = 0; in_ < NIN; ++in_) {
                f32x4 z = {0.f, 0.f, 0.f, 0.f};
                s[jm][in_] = z;
            }
        __builtin_amdgcn_s_setprio(1);
        #pragma unroll
        for (int jm = 0; jm < 2; ++jm)
            #pragma unroll
            for (int ks = 0; ks < 2; ++ks)
                #pragma unroll
                for (int in_ = 0; in_ < NIN; ++in_) {
                    s[jm][in_] = MFMA16(kf[jm][ks], qf[in_][ks][0], s[jm][in_]);
                    s[jm][in_] = MFMA16(kf[jm][ks], qf[in_][ks][1], s[jm][in_]);
                }
        __builtin_amdgcn_s_setprio(0);

        // fixed-max softmax: P = exp2(s); lsum per-lane partial
        #pragma unroll
        for (int in_ = 0; in_ < NIN; ++in_) {
            float ls = 0.f;
            #pragma unroll
            for (int jm = 0; jm < 2; ++jm)
                #pragma unroll
                for (int r = 0; r < 4; ++r) {
                    float p = EXP2(s[jm][in_][r]);
                    s[jm][in_][r] = p; ls += p;
                }
            lsum[in_] += ls;

            int w00 = (int)pkh(s[0][in_][0], s[0][in_][1]);
            int w01 = (int)pkh(s[0][in_][2], s[0][in_][3]);
            int w10 = (int)pkh(s[1][in_][0], s[1][in_][1]);
            int w11 = (int)pkh(s[1][in_][2], s[1][in_][3]);

            int a0 = __shfl(w00, idx0, 64), a1 = __shfl(w01, idx0, 64);
            int a2 = __shfl(w00, idx1, 64), a3 = __shfl(w01, idx1, 64);
            int b0 = __shfl(w10, idx0, 64), b1 = __shfl(w11, idx0, 64);
            int b2 = __shfl(w10, idx1, 64), b3 = __shfl(w11, idx1, 64);
            F8U fu;
            fu.u[0] = (uint32_t)(topTile ? b0 : a0);
            fu.u[1] = (uint32_t)(topTile ? b1 : a1);
            fu.u[2] = (uint32_t)(topTile ? b2 : a2);
            fu.u[3] = (uint32_t)(topTile ? b3 : a3);

            __builtin_amdgcn_s_setprio(1);
            #pragma unroll
            for (int cm = 0; cm < 4; ++cm)
                acc[cm][in_] = MFMA16(vf[cm], fu.v, acc[cm][in_]);
            __builtin_amdgcn_s_setprio(0);
        }

        __syncthreads();
    }

    // epilogue: reduce lsum across g-groups, O/l -> fp16 hi, transposed
    #pragma unroll
    for (int in_ = 0; in_ < NIN; ++in_) {
        float lt = lsum[in_];
        lt += __shfl_xor(lt, 16, 64);
        lt += __shfl_xor(lt, 32, 64);
        float inv = 1.0f / lt;
        int i = i0 + 16 * in_ + ln;
        #pragma unroll
        for (int cm = 0; cm < 4; ++cm) {
            f32x4 o4 = acc[cm][in_] * inv;
            const int cp = 32 * h + 8 * cm + 2 * g;
            const size_t idx = ((size_t)b * 256 + cp) * P + i;
            oh[idx] = pkh(o4[0], o4[1]);
            oh[idx + P] = pkh(o4[2], o4[3]);
        }
    }
}

// ---------------------------------------------------------------------------
// Output projection: out = Wo_h @ O_h + bo (1-term fp16 MFMA), coalesced
// B-loads from transposed oh [b][cp][pos].
// ---------------------------------------------------------------------------
__global__ __launch_bounds__(256, 4) void out_proj(
    const unsigned short* __restrict__ woh, const uint32_t* __restrict__ oh,
    const float* __restrict__ bo, float* __restrict__ out)
{
    const int wid = threadIdx.x >> 6;
    const int l = threadIdx.x & 63;
    const int ln = l & 15, g = l >> 4;
    const int ibase = blockIdx.x * 128 + wid * 32;
    const int otile = blockIdx.y * 32;
    const int b = blockIdx.z;

    f32x4 acc[2][2];
    #pragma unroll
    for (int mt = 0; mt < 2; ++mt)
        #pragma unroll
        for (int nt = 0; nt < 2; ++nt) {
            f32x4 z = {0.f, 0.f, 0.f, 0.f};
            acc[mt][nt] = z;
        }

    #pragma unroll
    for (int ks = 0; ks < 16; ++ks) {
        const int c0 = 32 * ks + 8 * g;
        const int cp0 = c0 >> 1;
        f16x8 wf[2];
        #pragma unroll
        for (int mt = 0; mt < 2; ++mt)
            wf[mt] = *reinterpret_cast<const f16x8*>(
                woh + (size_t)(otile + 16 * mt + ln) * HID + c0);
        #pragma unroll
        for (int nt = 0; nt < 2; ++nt) {
            const int pos = ibase + 16 * nt + ln;
            const size_t obase = ((size_t)b * 256 + cp0) * P + pos;
            F8U bh;
            bh.u[0] = oh[obase];
            bh.u[1] = oh[obase + P];
            bh.u[2] = oh[obase + 2 * (size_t)P];
            bh.u[3] = oh[obase + 3 * (size_t)P];
            #pragma unroll
            for (int mt = 0; mt < 2; ++mt)
                acc[mt][nt] = MFMA16(wf[mt], bh.v, acc[mt][nt]);
        }
    }

    #pragma unroll
    for (int mt = 0; mt < 2; ++mt)
        #pragma unroll
        for (int r = 0; r < 4; ++r) {
            int o_ = otile + 16 * mt + 4 * g + r;
            float bv = bo[o_];
            #pragma unroll
            for (int nt = 0; nt < 2; ++nt)
                out[((size_t)b * CQ + o_) * P + ibase + 16 * nt + ln] =
                    acc[mt][nt][r] + bv;
        }
}

extern "C" void kernel_launch(void* const* d_in, const int* in_sizes, int n_in,
                              void* d_out, int out_size, void* d_ws, size_t ws_size,
                              hipStream_t stream) {
    (void)in_sizes; (void)n_in; (void)out_size; (void)ws_size;
    const float* x   = (const float*)d_in[0];
    const float* ctx = (const float*)d_in[1];
    const float* Wq  = (const float*)d_in[2];
    const float* Wk  = (const float*)d_in[3];
    const float* Wv  = (const float*)d_in[4];
    const float* Wo  = (const float*)d_in[5];
    const float* bo  = (const float*)d_in[6];
    float* out = (float*)d_out;

    // Workspace (ushort units), no aliasing needed (~60 MB total).
    unsigned short* ws = (unsigned short*)d_ws;
    uint32_t* oh        = (uint32_t*)ws;             // 4194304 u32 = 8388608 us
    unsigned short* qh  = ws + (size_t)8388608;      // 8388608
    unsigned short* ql  = qh + (size_t)8388608;      // 8388608
    unsigned short* kh  = ql + (size_t)8388608;      // 2097152
    unsigned short* vh  = kh + (size_t)2097152;      // 2097152
    unsigned short* woh = vh + (size_t)2097152;      // 131072
    unsigned short* wqh = woh + (size_t)131072;      // 131072
    unsigned short* wkh = wqh + (size_t)131072;      // 262144
    unsigned short* wvh = wkh + (size_t)262144;      // 262144

    dim3 blk(256);
    // 1. weight splits (hi only, octet layout)
    split_all<<<dim3(768), blk, 0, stream>>>(Wq, Wk, Wv, Wo, wqh, wkh, wvh, woh);
    // 2. fused Q/K/V projections (1-term MFMA, raw fp32 inputs)
    proj_qkv<<<dim3(96, 4, BATCH), blk, 0, stream>>>(
        wqh, wkh, wvh, x, ctx, qh, ql, kh, vh);
    // 3. attention -> oh transposed
    attn_mfma<<<dim3(HEADS * BATCH, P / 256), blk, 0, stream>>>(
        qh, ql, kh, vh, oh);
    // 4. out = Wo @ O + bo
    out_proj<<<dim3(P / 128, CQ / 32, BATCH), blk, 0, stream>>>(
        woh, oh, bo, out);
}